// Round 1
// baseline (587.462 us; speedup 1.0000x reference)
//
#include <hip/hip_runtime.h>
#include <hip/hip_bf16.h>
#include <cstdint>
#include <cstddef>
#include <math.h>
#include <type_traits>

typedef __bf16 bf16;
typedef __bf16 bf16x4 __attribute__((ext_vector_type(4)));
typedef __bf16 bf16x8 __attribute__((ext_vector_type(8)));
typedef float  f32x4  __attribute__((ext_vector_type(4)));
typedef unsigned u32x2 __attribute__((ext_vector_type(2)));

// Shapes: B=4, T=4096, D=1024, H=8, DH=128, BUCKETS=64, BSZ=64, BH=32
// ws (128 MiB): q[bh][u][i][e] | k[bh][u][i][e] | vT[bh][u][e][i] | xa
// PRE path (fp32 out, out_size = 64 MiB):
//   xa scratch after gemm1: bkr (1 MiB) | R_buf (512 KiB)   [dead before attn writes aout]
//   d_out scratch: wqkv_bf 6 MiB (dead after gemm1), then kre 32 MiB | vre 32 MiB
//     (dead before gemm2 writes d_out)
// non-PRE fallback keeps the old layout + in-attn weighted sum.

__device__ inline bool input_is_fp32(const void* x) {
  const unsigned short* u = (const unsigned short*)x;
  const int lane = threadIdx.x & 63;
  const int e = (u[lane] >> 7) & 0xFF;
  return __ballot(e >= 137) != 0ULL;
}

__device__ inline float ldx(const void* p, size_t i, bool f32) {
  return f32 ? ((const float*)p)[i] : (float)((const bf16*)p)[i];
}

template<typename T>
__device__ inline bf16x8 ld8bf(const void* p, size_t i) {
  if constexpr (std::is_same<T, float>::value) {
    const f32x4* q = (const f32x4*)((const float*)p + i);
    const f32x4 a = q[0], b = q[1];
    bf16x8 r;
    r[0]=(bf16)a[0]; r[1]=(bf16)a[1]; r[2]=(bf16)a[2]; r[3]=(bf16)a[3];
    r[4]=(bf16)b[0]; r[5]=(bf16)b[1]; r[6]=(bf16)b[2]; r[7]=(bf16)b[3];
    return r;
  } else {
    return *(const bf16x8*)((const bf16*)p + i);
  }
}

// async global->LDS, 16 B per lane; LDS dest = wave-uniform base + lane*16
__device__ __forceinline__ void gload16(const void* g, void* l) {
  __builtin_amdgcn_global_load_lds(
      (__attribute__((address_space(1))) void*)g,
      (__attribute__((address_space(3))) void*)l, 16, 0, 0);
}

// ---------------------------------------------------------------------------
// dtype-flexible fp32/bf16 -> bf16 copy. One thread = 8 elements.
// ---------------------------------------------------------------------------
__global__ __launch_bounds__(256)
void convert_to_bf16(const void* __restrict__ src, bf16* __restrict__ dst,
                     const void* __restrict__ xdet) {
  const bool f32 = input_is_fp32(xdet);
  const size_t i = ((size_t)blockIdx.x * 256 + threadIdx.x) * 8;
  if (f32) *(bf16x8*)&dst[i] = ld8bf<float>(src, i);
  else     *(bf16x8*)&dst[i] = ld8bf<bf16 >(src, i);
}

// ---------------------------------------------------------------------------
// GEMM: C[m][n] = sum_k A[m][k]*B[n][k], both bf16 K-contiguous.
// 128x128 tile, BK=32, 4 waves, 16x16x32 MFMA, m97-style global_load_lds x16.
// EPI=0: scatter into q/k ([u][i][e]) and vT ([u][e][i], 8-B packed).
// EPI=1: bias add, row-major C0, output dtype = detected input dtype.
// ---------------------------------------------------------------------------
template<int EPI>
__global__ __launch_bounds__(256)
void gemm_bt(const bf16* __restrict__ A, const bf16* __restrict__ Bm,
             const void* __restrict__ bias,
             void* __restrict__ C0, bf16* __restrict__ C1, bf16* __restrict__ C2,
             const void* __restrict__ xdet, int M, int N, int K)
{
  __shared__ __align__(16) bf16 As[128*32];
  __shared__ __align__(16) bf16 Bs[128*32];
  const int tid  = threadIdx.x;
  const int wave = tid >> 6, lane = tid & 63;
  const int m0 = blockIdx.y * 128, n0 = blockIdx.x * 128;
  const int wm = (wave >> 1) * 64, wn = (wave & 1) * 64;
  const int fr = lane & 15;
  const int fk = (lane >> 4) * 8;

  const int srow = wave * 16 + (lane >> 2);
  const int scol = (lane & 3) * 8;
  const bf16* gA = A  + (size_t)(m0 + srow) * K + scol;
  const bf16* gB = Bm + (size_t)(n0 + srow) * K + scol;
  bf16* lA = &As[wave * 16 * 32];
  bf16* lB = &Bs[wave * 16 * 32];

  f32x4 acc[4][4];
  #pragma unroll
  for (int a = 0; a < 4; ++a)
    #pragma unroll
    for (int b = 0; b < 4; ++b) { f32x4 z = {0.f, 0.f, 0.f, 0.f}; acc[a][b] = z; }

  for (int k0 = 0; k0 < K; k0 += 32) {
    __syncthreads();
    gload16(gA + k0,                  lA);
    gload16(gA + (size_t)64*K + k0,   lA + 64*32);
    gload16(gB + k0,                  lB);
    gload16(gB + (size_t)64*K + k0,   lB + 64*32);
    __syncthreads();                  // compiler drains vmcnt before barrier
    bf16x8 af[4], bfr[4];
    #pragma unroll
    for (int t = 0; t < 4; ++t) {
      af[t]  = *(const bf16x8*)&As[(wm + t*16 + fr)*32 + fk];
      bfr[t] = *(const bf16x8*)&Bs[(wn + t*16 + fr)*32 + fk];
    }
    #pragma unroll
    for (int tm = 0; tm < 4; ++tm)
      #pragma unroll
      for (int tn = 0; tn < 4; ++tn)
        acc[tm][tn] = __builtin_amdgcn_mfma_f32_16x16x32_bf16(af[tm], bfr[tn], acc[tm][tn], 0, 0, 0);
  }

  // C/D layout: col = lane&15, row = (lane>>4)*4 + reg
  const int cn = lane & 15, cr = (lane >> 4) * 4;
  if constexpr (EPI == 0) {
    const int sel = n0 >> 10;               // block-uniform (n0 mult of 128)
    const int cb  = (n0 & 1023) + wn;
    #pragma unroll
    for (int tm = 0; tm < 4; ++tm) {
      const int m = m0 + wm + tm*16 + cr;
      const int b = m >> 12, t = m & 4095;
      const int u = t >> 6,  i = t & 63;    // i..i+3 stay in-bucket
      #pragma unroll
      for (int tn = 0; tn < 4; ++tn) {
        const int c = cb + tn*16 + cn;
        const int h = c >> 7, e = c & 127;
        const size_t bhu = (size_t)((b*8 + h)*64 + u);
        if (sel == 2) {                     // vT [u][e][i]: one 8-B store
          bf16x4 w;
          #pragma unroll
          for (int r = 0; r < 4; ++r) w[r] = (bf16)acc[tm][tn][r];
          *(bf16x4*)&C2[(bhu*128 + e)*64 + i] = w;
        } else {                            // q/k [u][i][e]
          bf16* dst = (sel == 0) ? (bf16*)C0 : C1;
          #pragma unroll
          for (int r = 0; r < 4; ++r)
            dst[(bhu*64 + i + r)*128 + e] = (bf16)acc[tm][tn][r];
        }
      }
    }
  } else {
    const bool f32o = input_is_fp32(xdet);
    #pragma unroll
    for (int tm = 0; tm < 4; ++tm) {
      #pragma unroll
      for (int tn = 0; tn < 4; ++tn) {
        #pragma unroll
        for (int r = 0; r < 4; ++r) {
          const int m = m0 + wm + tm*16 + cr + r;
          const int n = n0 + wn + tn*16 + cn;
          const float val = acc[tm][tn][r] + ldx(bias, n, f32o);
          if (f32o) ((float*)C0)[(size_t)m*N + n] = val;
          else      ((bf16*)C0)[(size_t)m*N + n] = (bf16)val;
        }
      }
    }
  }
}

// ---------------------------------------------------------------------------
// bksum: bkr[bh][u][e] = sum_i k[bh][u][i][e]. grid (8,32), 128 threads.
// ---------------------------------------------------------------------------
__global__ __launch_bounds__(128)
void bksum(const bf16* __restrict__ k_ws, float* __restrict__ bkr_g)
{
  const int ug = blockIdx.x, bh = blockIdx.y, t = threadIdx.x;
  const int ul = t >> 4, e0 = (t & 15) * 8;
  const int u = ug * 8 + ul;
  const bf16* p = k_ws + ((size_t)bh*64 + u)*8192 + e0;
  float acc[8];
  #pragma unroll
  for (int j = 0; j < 8; ++j) acc[j] = 0.f;
  for (int i = 0; i < 64; ++i) {
    bf16x8 kv = *(const bf16x8*)&p[i*128];
    #pragma unroll
    for (int j = 0; j < 8; ++j) acc[j] += (float)kv[j];
  }
  float* dst = bkr_g + (size_t)bh*8192 + u*128 + e0;
  #pragma unroll
  for (int j = 0; j < 8; ++j) dst[j] = acc[j];
}

// ---------------------------------------------------------------------------
// Sinkhorn R per bh (32 blocks, 256 threads). Gumbel inner expr in fp64.
// ---------------------------------------------------------------------------
__global__ __launch_bounds__(256)
void sinkhorn_R(const float* __restrict__ bkr_g, const void* __restrict__ sort_w,
                const void* __restrict__ noise, float* __restrict__ R_buf,
                const void* __restrict__ xdet)
{
  const bool f32 = input_is_fp32(xdet);
  const int bh = blockIdx.x, h = bh & 7, tid = threadIdx.x;
  __shared__ float bkr[64*128];
  __shared__ float ew[128*64];
  __shared__ float R[64*65];

  for (int f = tid; f < 64*128; f += 256) bkr[f] = bkr_g[(size_t)bh*8192 + f];
  for (int f = tid; f < 128*64; f += 256) ew[f] = ldx(sort_w, (size_t)h*8192 + f, f32);
  __syncthreads();

  for (int f = tid; f < 64*64; f += 256) {
    const int u = f >> 6, v = f & 63;
    float s = 0.f;
    for (int e = 0; e < 128; ++e) s += bkr[u*128 + e] * ew[e*64 + v];
    s = fmaxf(s, 0.f);
    const float r  = logf(s + 1e-6f);
    const double nz = (double)ldx(noise, ((size_t)bh*64 + u)*64 + v, f32);
    const double t1 = log(nz + 1e-4);
    const double t2 = fmax(-t1 + 1e-4, 1e-30);
    const float g = (float)(-log(t2));
    R[u*65 + v] = (r + g) * (1.f / 0.75f);
  }
  __syncthreads();

  for (int it = 0; it < 5; ++it) {
    if (tid < 64) {
      float mx = -1e30f;
      for (int v = 0; v < 64; ++v) mx = fmaxf(mx, R[tid*65 + v]);
      float s = 0.f;
      for (int v = 0; v < 64; ++v) s += expf(R[tid*65 + v] - mx);
      const float l = mx + logf(s);
      for (int v = 0; v < 64; ++v) R[tid*65 + v] -= l;
    }
    __syncthreads();
    if (tid < 64) {
      float mx = -1e30f;
      for (int u = 0; u < 64; ++u) mx = fmaxf(mx, R[u*65 + tid]);
      float s = 0.f;
      for (int u = 0; u < 64; ++u) s += expf(R[u*65 + tid] - mx);
      const float l = mx + logf(s);
      for (int u = 0; u < 64; ++u) R[u*65 + tid] -= l;
    }
    __syncthreads();
  }

  for (int f = tid; f < 64*64; f += 256) {
    const int u = f >> 6, v = f & 63;
    R_buf[(size_t)bh*4096 + f] = (u > v) ? expf(R[u*65 + v]) : 0.f;
  }
}

// ---------------------------------------------------------------------------
// permute_kv: Out[bh][u][f] = sum_v R[bh][u][v] * X[bh][v][f]  (f = 8192/bucket)
// One block = (bh, 256-f chunk, tensor z). R as bf16 hi+lo (K=128) for ~fp32
// weight precision. X staged into 16-col subtiles; v-contiguous B-frags via
// ds_read_b64_tr_b16 (4 bf16 at 32-B row stride).
// ---------------------------------------------------------------------------
__global__ __launch_bounds__(256)
void permute_kv(const float* __restrict__ R_buf,
                const bf16* __restrict__ Xk, const bf16* __restrict__ Xv,
                bf16* __restrict__ Ok, bf16* __restrict__ Ov)
{
  const int tid = threadIdx.x;
  const int bh  = blockIdx.y;
  const int f0  = blockIdx.x * 256;
  const bf16* X = blockIdx.z ? Xv : Xk;
  bf16*       O = blockIdx.z ? Ov : Ok;

  __shared__ __align__(16) bf16 A_lds[64*136];    // R hi|lo, padded stride 136
  __shared__ __align__(16) bf16 X_lds[16*1048];   // 16 fgrps x [64 v][16 f], fgrp stride 1048 (bank-stagger)

  // stage X tile [64 v][256 f]: fgrp = (f-f0)>>4 holds rows of 16 bf16 (32 B; tr stride)
  {
    const bf16* Xg = X + (size_t)bh*524288 + f0;
    const int vb = tid >> 5, c = tid & 31;
    const int dst = (c >> 1)*1048 + (c & 1)*8;
    #pragma unroll
    for (int p = 0; p < 8; ++p) {
      const int v = vb + p*8;
      *(bf16x8*)&X_lds[dst + v*16] = *(const bf16x8*)&Xg[(size_t)v*8192 + c*8];
    }
  }
  // stage R split: A[u][v]=hi(R), A[u][64+v]=lo(R)
  {
    const float* Rg = R_buf + (size_t)bh*4096;
    #pragma unroll
    for (int p = 0; p < 16; ++p) {
      const int idx = tid + p*256;
      const int uu = idx >> 6, vv = idx & 63;
      const float r = Rg[idx];
      const bf16 hi = (bf16)r;
      const float lo = r - (float)hi;
      A_lds[uu*136 + vv]      = hi;
      A_lds[uu*136 + 64 + vv] = (bf16)lo;
    }
  }
  __syncthreads();

  const int lane = tid & 63, wave = tid >> 6;
  const int fr = lane & 15, quad = lane >> 4;

  bf16x8 af[4][4];
  #pragma unroll
  for (int mt = 0; mt < 4; ++mt)
    #pragma unroll
    for (int ks = 0; ks < 4; ++ks)
      af[mt][ks] = *(const bf16x8*)&A_lds[(mt*16 + fr)*136 + ks*32 + quad*8];

  f32x4 acc[4][4];
  #pragma unroll
  for (int a = 0; a < 4; ++a)
    #pragma unroll
    for (int b = 0; b < 4; ++b) { f32x4 z = {0.f,0.f,0.f,0.f}; acc[a][b] = z; }

  #pragma unroll
  for (int nt = 0; nt < 4; ++nt) {
    const int g = wave*4 + nt;
    const unsigned addr = (unsigned)(uintptr_t)&X_lds[g*1048 + quad*8*16 + fr];
    u32x2 p0, p1, p2, p3;
    asm volatile(
      "ds_read_b64_tr_b16 %0, %4\n"
      "ds_read_b64_tr_b16 %1, %4 offset:128\n"
      "ds_read_b64_tr_b16 %2, %4 offset:1024\n"
      "ds_read_b64_tr_b16 %3, %4 offset:1152\n"
      : "=&v"(p0), "=&v"(p1), "=&v"(p2), "=&v"(p3)
      : "v"(addr));
    asm volatile("s_waitcnt lgkmcnt(0)" ::: "memory");
    __builtin_amdgcn_sched_barrier(0);
    union { u32x2 u[2]; bf16x8 v; } c0, c1;
    c0.u[0] = p0; c0.u[1] = p1;               // b0: v = 0..31 slice (quad*8 + j)
    c1.u[0] = p2; c1.u[1] = p3;               // b1: v = 32..63 slice
    const bf16x8 b0 = c0.v, b1 = c1.v;
    #pragma unroll
    for (int mt = 0; mt < 4; ++mt) {
      acc[mt][nt] = __builtin_amdgcn_mfma_f32_16x16x32_bf16(af[mt][0], b0, acc[mt][nt], 0, 0, 0);
      acc[mt][nt] = __builtin_amdgcn_mfma_f32_16x16x32_bf16(af[mt][1], b1, acc[mt][nt], 0, 0, 0);
      acc[mt][nt] = __builtin_amdgcn_mfma_f32_16x16x32_bf16(af[mt][2], b0, acc[mt][nt], 0, 0, 0);  // lo * v0..31
      acc[mt][nt] = __builtin_amdgcn_mfma_f32_16x16x32_bf16(af[mt][3], b1, acc[mt][nt], 0, 0, 0);  // lo * v32..63
    }
  }

  bf16* Og = O + (size_t)bh*524288 + f0;
  #pragma unroll
  for (int mt = 0; mt < 4; ++mt)
    #pragma unroll
    for (int nt = 0; nt < 4; ++nt)
      #pragma unroll
      for (int r = 0; r < 4; ++r)
        Og[(size_t)(mt*16 + quad*4 + r)*8192 + wave*64 + nt*16 + fr] = (bf16)acc[mt][nt][r];
}

// ---------------------------------------------------------------------------
// MFMA bucketed attention. One block per (bh,u), 256 threads.
// PRE=1: kre/vre precomputed in global (streaming; every byte read once).
// PRE=0: legacy in-block weighted sum (small-out fallback).
// ---------------------------------------------------------------------------
template<bool PRE>
__global__ __launch_bounds__(256)
void attn_mfma(const bf16* __restrict__ q_ws, const bf16* __restrict__ k_ws,
               const bf16* __restrict__ vT_ws, const float* __restrict__ R_buf,
               const bf16* __restrict__ kre_g, const bf16* __restrict__ vre_g,
               bf16* __restrict__ aout)
{
  const int u = 63 - blockIdx.x, bh = blockIdx.y, tid = threadIdx.x;
  const int lane = tid & 63, wave = tid >> 6;
  const int fr = lane & 15, quad = lane >> 4;

  constexpr int SMEM_SZ = PRE ? 34048 : 69888;
  __shared__ __align__(16) unsigned char smem[SMEM_SZ];
  bf16*  kre_s = (bf16*)smem;                                   // !PRE only
  bf16*  vre_s = (bf16*)(smem + (PRE ? 0 : 17408));             // !PRE only
  float* sc    = (float*)(smem + (PRE ? 0 : 35840));
  bf16*  pA    = (bf16*)sc;
  float* Rrow  = (float*)(smem + (PRE ? 0 : 69632));            // !PRE only

  const size_t tileq = ((size_t)bh*64 + u) * 8192;

  if constexpr (!PRE) {
    if (tid < 64) Rrow[tid] = R_buf[(size_t)bh*4096 + (size_t)u*64 + tid];
    __syncthreads();
    float ak[32], av[32];
    #pragma unroll
    for (int r = 0; r < 32; ++r) { ak[r] = 0.f; av[r] = 0.f; }
    for (int v = 0; v < u; ++v) {
      const float rv = Rrow[v];
      const bf16* kp = k_ws  + ((size_t)bh*64 + v)*8192;
      const bf16* vp = vT_ws + ((size_t)bh*64 + v)*8192;
      #pragma unroll
      for (int r = 0; r < 4; ++r) {
        bf16x8 kv = *(const bf16x8*)&kp[r*2048 + tid*8];
        bf16x8 vv = *(const bf16x8*)&vp[r*2048 + tid*8];
        #pragma unroll
        for (int j = 0; j < 8; ++j) {
          ak[r*8 + j] += rv * (float)kv[j];
          av[r*8 + j] += rv * (float)vv[j];
        }
      }
    }
    #pragma unroll
    for (int r = 0; r < 4; ++r) {
      const int f = r*2048 + tid*8;
      {
        bf16x8 w;
        #pragma unroll
        for (int j = 0; j < 8; ++j) w[j] = (bf16)ak[r*8 + j];
        *(bf16x8*)&kre_s[(f >> 7)*136 + (f & 127)] = w;
      }
      {
        bf16x8 w;
        #pragma unroll
        for (int j = 0; j < 8; ++j) w[j] = (bf16)av[r*8 + j];
        *(bf16x8*)&vre_s[(f >> 6)*72 + (f & 63)] = w;
      }
    }
    __syncthreads();
  }

  {
    f32x4 dacc[4][2];
    #pragma unroll
    for (int mt = 0; mt < 4; ++mt)
      #pragma unroll
      for (int nt = 0; nt < 2; ++nt) { f32x4 z = {0.f,0.f,0.f,0.f}; dacc[mt][nt] = z; }
    #pragma unroll
    for (int ks = 0; ks < 4; ++ks) {
      bf16x8 afr[4];
      #pragma unroll
      for (int mt = 0; mt < 4; ++mt)
        afr[mt] = *(const bf16x8*)&q_ws[tileq + (size_t)(mt*16 + fr)*128 + ks*32 + quad*8];
      #pragma unroll
      for (int nt = 0; nt < 2; ++nt) {
        const int j = wave*32 + nt*16 + fr;
        bf16x8 bfr;
        if constexpr (PRE) {
          if (wave < 2) bfr = *(const bf16x8*)&kre_g[tileq + (size_t)j*128 + ks*32 + quad*8];
          else          bfr = *(const bf16x8*)&k_ws[tileq + (size_t)(j - 64)*128 + ks*32 + quad*8];
        } else {
          if (wave < 2) bfr = *(const bf16x8*)&kre_s[j*136 + ks*32 + quad*8];
          else          bfr = *(const bf16x8*)&k_ws[tileq + (size_t)(j - 64)*128 + ks*32 + quad*8];
        }
        #pragma unroll
        for (int mt = 0; mt < 4; ++mt)
          dacc[mt][nt] = __builtin_amdgcn_mfma_f32_16x16x32_bf16(afr[mt], bfr, dacc[mt][nt], 0, 0, 0);
      }
    }
    #pragma unroll
    for (int mt = 0; mt < 4; ++mt)
      #pragma unroll
      for (int nt = 0; nt < 2; ++nt)
        #pragma unroll
        for (int r = 0; r < 4; ++r)
          sc[(mt*16 + quad*4 + r)*132 + wave*32 + nt*16 + fr] = dacc[mt][nt][r] * 0.03125f;
  }
  __syncthreads();

  {
    const int i = tid >> 2, jc = tid & 3;
    float pv[32];
    float mx = -1e30f;
    #pragma unroll
    for (int t = 0; t < 32; ++t) { pv[t] = sc[i*132 + jc + t*4]; mx = fmaxf(mx, pv[t]); }
    mx = fmaxf(mx, __shfl_xor(mx, 1));
    mx = fmaxf(mx, __shfl_xor(mx, 2));
    float s = 0.f;
    #pragma unroll
    for (int t = 0; t < 32; ++t) { pv[t] = expf(pv[t] - mx); s += pv[t]; }
    s += __shfl_xor(s, 1);
    s += __shfl_xor(s, 2);
    const float inv = 1.f / s;
    __syncthreads();
    #pragma unroll
    for (int t = 0; t < 32; ++t) pA[i*136 + jc + t*4] = (bf16)(pv[t] * inv);
  }
  __syncthreads();

  {
    f32x4 oacc[4][2];
    #pragma unroll
    for (int mt = 0; mt < 4; ++mt)
      #pragma unroll
      for (int nt = 0; nt < 2; ++nt) { f32x4 z = {0.f,0.f,0.f,0.f}; oacc[mt][nt] = z; }
    #pragma unroll
    for (int ks = 0; ks < 4; ++ks) {
      bf16x8 afr[4];
      #pragma unroll
      for (int mt = 0; mt < 4; ++mt)
        afr[mt] = *(const bf16x8*)&pA[(mt*16 + fr)*136 + ks*32 + quad*8];
      #pragma unroll
      for (int nt = 0; nt < 2; ++nt) {
        const int e = wave*32 + nt*16 + fr;
        bf16x8 bfr;
        if constexpr (PRE) {
          if (ks < 2) bfr = *(const bf16x8*)&vre_g[tileq + (size_t)e*64 + ks*32 + quad*8];
          else        bfr = *(const bf16x8*)&vT_ws[tileq + (size_t)e*64 + (ks - 2)*32 + quad*8];
        } else {
          if (ks < 2) bfr = *(const bf16x8*)&vre_s[e*72 + ks*32 + quad*8];
          else        bfr = *(const bf16x8*)&vT_ws[tileq + (size_t)e*64 + (ks - 2)*32 + quad*8];
        }
        #pragma unroll
        for (int mt = 0; mt < 4; ++mt)
          oacc[mt][nt] = __builtin_amdgcn_mfma_f32_16x16x32_bf16(afr[mt], bfr, oacc[mt][nt], 0, 0, 0);
      }
    }
    __syncthreads();
    #pragma unroll
    for (int mt = 0; mt < 4; ++mt)
      #pragma unroll
      for (int nt = 0; nt < 2; ++nt)
        #pragma unroll
        for (int r = 0; r < 4; ++r)
          pA[(mt*16 + quad*4 + r)*136 + wave*32 + nt*16 + fr] = (bf16)oacc[mt][nt][r];
  }
  __syncthreads();

  {
    const int b = bh >> 3, h = bh & 7;
    #pragma unroll
    for (int r = 0; r < 4; ++r) {
      const int f = r*2048 + tid*8;
      const int i = f >> 7, e0 = f & 127;
      bf16x8 w = *(const bf16x8*)&pA[i*136 + e0];
      *(bf16x8*)&aout[((size_t)(b*4096 + u*64 + i))*1024 + h*128 + e0] = w;
    }
  }
}

// ---------------------------------------------------------------------------
extern "C" void kernel_launch(void* const* d_in, const int* in_sizes, int n_in,
                              void* d_out, int out_size, void* d_ws, size_t ws_size,
                              hipStream_t stream)
{
  (void)in_sizes; (void)n_in; (void)ws_size;
  const void* x      = d_in[0];   // (4,4096,1024)
  const void* w_qkv  = d_in[1];   // (3072,1024)
  const void* sort_w = d_in[2];   // (1,8,128,64)
  const void* w_out  = d_in[3];   // (1024,1024)
  const void* b_out  = d_in[4];   // (1024,)
  const void* noise  = d_in[5];   // (32,64,64)

  char* ws = (char*)d_ws;
  const size_t TEN = (size_t)32*64*64*128;     // 16,777,216 elements
  bf16* q_ws  = (bf16*)ws;
  bf16* k_ws  = q_ws + TEN;
  bf16* vT_ws = k_ws + TEN;                    // [bh][u][e][i]
  bf16* xa_ws = vT_ws + TEN;                   // x-as-bf16, later attn out (b,t,d)
  bf16* wqkv_bf = (bf16*)((char*)d_out + (1536<<10));  // 6 MiB, dead after gemm1
  bf16* wout_bf = k_ws;                                // reused after attn

  const bool pre = (out_size >= 67108864);     // 64 MiB fp32 output

  if (pre) {
    // scratch: bkr/R in the xa region (dead between gemm1 and attn);
    // kre/vre fill the whole d_out (dead before gemm2).
    float* bkr_g = (float*)xa_ws;
    float* R_buf = (float*)((char*)xa_ws + (1<<20));
    bf16*  kre   = (bf16*)d_out;
    bf16*  vre   = (bf16*)d_out + TEN;

    convert_to_bf16<<<8192, 256, 0, stream>>>(x, xa_ws, x);
    convert_to_bf16<<<1536, 256, 0, stream>>>(w_qkv, wqkv_bf, x);

    gemm_bt<0><<<dim3(24,128), 256, 0, stream>>>(xa_ws, wqkv_bf, nullptr,
                                                 q_ws, k_ws, vT_ws, x, 16384, 3072, 1024);

    bksum<<<dim3(8,32), 128, 0, stream>>>(k_ws, bkr_g);
    sinkhorn_R<<<32, 256, 0, stream>>>(bkr_g, sort_w, noise, R_buf, x);

    permute_kv<<<dim3(32,32,2), 256, 0, stream>>>(R_buf, k_ws, vT_ws, kre, vre);

    attn_mfma<true><<<dim3(64,32), 256, 0, stream>>>(q_ws, k_ws, vT_ws, nullptr,
                                                     kre, vre, xa_ws);

    convert_to_bf16<<<512, 256, 0, stream>>>(w_out, wout_bf, x);
    gemm_bt<1><<<dim3(8,128), 256, 0, stream>>>(xa_ws, wout_bf, b_out,
                                                d_out, nullptr, nullptr, x, 16384, 1024, 1024);
  } else {
    // legacy path (bf16 output => only 32 MiB of d_out scratch available)
    float* R_buf = (float*)d_out;                           // 512 KiB
    float* bkr_g = (float*)((char*)d_out + (512<<10));      // 1 MiB

    convert_to_bf16<<<8192, 256, 0, stream>>>(x, xa_ws, x);
    convert_to_bf16<<<1536, 256, 0, stream>>>(w_qkv, wqkv_bf, x);

    gemm_bt<0><<<dim3(24,128), 256, 0, stream>>>(xa_ws, wqkv_bf, nullptr,
                                                 q_ws, k_ws, vT_ws, x, 16384, 3072, 1024);

    bksum<<<dim3(8,32), 128, 0, stream>>>(k_ws, bkr_g);
    sinkhorn_R<<<32, 256, 0, stream>>>(bkr_g, sort_w, noise, R_buf, x);

    attn_mfma<false><<<dim3(64,32), 256, 0, stream>>>(q_ws, k_ws, vT_ws, R_buf,
                                                      nullptr, nullptr, xa_ws);

    convert_to_bf16<<<512, 256, 0, stream>>>(w_out, wout_bf, x);
    gemm_bt<1><<<dim3(8,128), 256, 0, stream>>>(xa_ws, wout_bf, b_out,
                                                d_out, nullptr, nullptr, x, 16384, 1024, 1024);
  }
}

// Round 3
// 479.236 us; speedup vs baseline: 1.2258x; 1.2258x over previous
//
#include <hip/hip_runtime.h>
#include <hip/hip_bf16.h>
#include <cstdint>
#include <cstddef>
#include <math.h>
#include <type_traits>

typedef __bf16 bf16;
typedef __bf16 bf16x4 __attribute__((ext_vector_type(4)));
typedef __bf16 bf16x8 __attribute__((ext_vector_type(8)));
typedef float  f32x4  __attribute__((ext_vector_type(4)));
typedef unsigned u32x2 __attribute__((ext_vector_type(2)));

// Shapes: B=4, T=4096, D=1024, H=8, DH=128, BUCKETS=64, BSZ=64, BH=32
// ws (128 MiB): q[bh][u][i][e] | k[bh][u][i][e] | vT[bh][u][e][i] | xa
// xa region (32 MiB): x-as-bf16 (dead after gemm1) -> bkr@+30Mi, R@+31Mi
//   (dead after 2nd permute_kv) -> aout (attn output, b-major)
// d_out scratch: wqkv_bf @+1.5Mi (dead after gemm1) -> kre 16Mi | vre 16Mi
//   per bh-half (dead before gemm2 writes d_out). Works for out_size >= 32 MiB.
// Schedule: gemm1 -> bksum -> sinkhorn -> [permute+attn] x 2 halves -> gemm2.

__device__ inline bool input_is_fp32(const void* x) {
  const unsigned short* u = (const unsigned short*)x;
  const int lane = threadIdx.x & 63;
  const int e = (u[lane] >> 7) & 0xFF;
  return __ballot(e >= 137) != 0ULL;
}

__device__ inline float ldx(const void* p, size_t i, bool f32) {
  return f32 ? ((const float*)p)[i] : (float)((const bf16*)p)[i];
}

template<typename T>
__device__ inline bf16x8 ld8bf(const void* p, size_t i) {
  if constexpr (std::is_same<T, float>::value) {
    const f32x4* q = (const f32x4*)((const float*)p + i);
    const f32x4 a = q[0], b = q[1];
    bf16x8 r;
    r[0]=(bf16)a[0]; r[1]=(bf16)a[1]; r[2]=(bf16)a[2]; r[3]=(bf16)a[3];
    r[4]=(bf16)b[0]; r[5]=(bf16)b[1]; r[6]=(bf16)b[2]; r[7]=(bf16)b[3];
    return r;
  } else {
    return *(const bf16x8*)((const bf16*)p + i);
  }
}

// async global->LDS, 16 B per lane; LDS dest = wave-uniform base + lane*16
__device__ __forceinline__ void gload16(const void* g, void* l) {
  __builtin_amdgcn_global_load_lds(
      (__attribute__((address_space(1))) void*)g,
      (__attribute__((address_space(3))) void*)l, 16, 0, 0);
}

// ---------------------------------------------------------------------------
// dtype-flexible fp32/bf16 -> bf16 copy. One thread = 8 elements.
// ---------------------------------------------------------------------------
__global__ __launch_bounds__(256)
void convert_to_bf16(const void* __restrict__ src, bf16* __restrict__ dst,
                     const void* __restrict__ xdet) {
  const bool f32 = input_is_fp32(xdet);
  const size_t i = ((size_t)blockIdx.x * 256 + threadIdx.x) * 8;
  if (f32) *(bf16x8*)&dst[i] = ld8bf<float>(src, i);
  else     *(bf16x8*)&dst[i] = ld8bf<bf16 >(src, i);
}

// ---------------------------------------------------------------------------
// GEMM: C[m][n] = sum_k A[m][k]*B[n][k], both bf16 K-contiguous.
// 128x128 tile, BK=32, 4 waves, 16x16x32 MFMA, m97-style global_load_lds x16.
// EPI=0: scatter into q/k ([u][i][e]) and vT ([u][e][i], 8-B packed).
// EPI=1: bias add, row-major C0, output dtype = detected input dtype.
// ---------------------------------------------------------------------------
template<int EPI>
__global__ __launch_bounds__(256)
void gemm_bt(const bf16* __restrict__ A, const bf16* __restrict__ Bm,
             const void* __restrict__ bias,
             void* __restrict__ C0, bf16* __restrict__ C1, bf16* __restrict__ C2,
             const void* __restrict__ xdet, int M, int N, int K)
{
  __shared__ __align__(16) bf16 As[128*32];
  __shared__ __align__(16) bf16 Bs[128*32];
  const int tid  = threadIdx.x;
  const int wave = tid >> 6, lane = tid & 63;
  const int m0 = blockIdx.y * 128, n0 = blockIdx.x * 128;
  const int wm = (wave >> 1) * 64, wn = (wave & 1) * 64;
  const int fr = lane & 15;
  const int fk = (lane >> 4) * 8;

  const int srow = wave * 16 + (lane >> 2);
  const int scol = (lane & 3) * 8;
  const bf16* gA = A  + (size_t)(m0 + srow) * K + scol;
  const bf16* gB = Bm + (size_t)(n0 + srow) * K + scol;
  bf16* lA = &As[wave * 16 * 32];
  bf16* lB = &Bs[wave * 16 * 32];

  f32x4 acc[4][4];
  #pragma unroll
  for (int a = 0; a < 4; ++a)
    #pragma unroll
    for (int b = 0; b < 4; ++b) { f32x4 z = {0.f, 0.f, 0.f, 0.f}; acc[a][b] = z; }

  for (int k0 = 0; k0 < K; k0 += 32) {
    __syncthreads();
    gload16(gA + k0,                  lA);
    gload16(gA + (size_t)64*K + k0,   lA + 64*32);
    gload16(gB + k0,                  lB);
    gload16(gB + (size_t)64*K + k0,   lB + 64*32);
    __syncthreads();                  // compiler drains vmcnt before barrier
    bf16x8 af[4], bfr[4];
    #pragma unroll
    for (int t = 0; t < 4; ++t) {
      af[t]  = *(const bf16x8*)&As[(wm + t*16 + fr)*32 + fk];
      bfr[t] = *(const bf16x8*)&Bs[(wn + t*16 + fr)*32 + fk];
    }
    #pragma unroll
    for (int tm = 0; tm < 4; ++tm)
      #pragma unroll
      for (int tn = 0; tn < 4; ++tn)
        acc[tm][tn] = __builtin_amdgcn_mfma_f32_16x16x32_bf16(af[tm], bfr[tn], acc[tm][tn], 0, 0, 0);
  }

  // C/D layout: col = lane&15, row = (lane>>4)*4 + reg
  const int cn = lane & 15, cr = (lane >> 4) * 4;
  if constexpr (EPI == 0) {
    const int sel = n0 >> 10;               // block-uniform (n0 mult of 128)
    const int cb  = (n0 & 1023) + wn;
    #pragma unroll
    for (int tm = 0; tm < 4; ++tm) {
      const int m = m0 + wm + tm*16 + cr;
      const int b = m >> 12, t = m & 4095;
      const int u = t >> 6,  i = t & 63;    // i..i+3 stay in-bucket
      #pragma unroll
      for (int tn = 0; tn < 4; ++tn) {
        const int c = cb + tn*16 + cn;
        const int h = c >> 7, e = c & 127;
        const size_t bhu = (size_t)((b*8 + h)*64 + u);
        if (sel == 2) {                     // vT [u][e][i]: one 8-B store
          bf16x4 w;
          #pragma unroll
          for (int r = 0; r < 4; ++r) w[r] = (bf16)acc[tm][tn][r];
          *(bf16x4*)&C2[(bhu*128 + e)*64 + i] = w;
        } else {                            // q/k [u][i][e]
          bf16* dst = (sel == 0) ? (bf16*)C0 : C1;
          #pragma unroll
          for (int r = 0; r < 4; ++r)
            dst[(bhu*64 + i + r)*128 + e] = (bf16)acc[tm][tn][r];
        }
      }
    }
  } else {
    const bool f32o = input_is_fp32(xdet);
    #pragma unroll
    for (int tm = 0; tm < 4; ++tm) {
      #pragma unroll
      for (int tn = 0; tn < 4; ++tn) {
        #pragma unroll
        for (int r = 0; r < 4; ++r) {
          const int m = m0 + wm + tm*16 + cr + r;
          const int n = n0 + wn + tn*16 + cn;
          const float val = acc[tm][tn][r] + ldx(bias, n, f32o);
          if (f32o) ((float*)C0)[(size_t)m*N + n] = val;
          else      ((bf16*)C0)[(size_t)m*N + n] = (bf16)val;
        }
      }
    }
  }
}

// ---------------------------------------------------------------------------
// bksum: bkr[bh][u][e] = sum_i k[bh][u][i][e]. grid (8,32), 128 threads.
// ---------------------------------------------------------------------------
__global__ __launch_bounds__(128)
void bksum(const bf16* __restrict__ k_ws, float* __restrict__ bkr_g)
{
  const int ug = blockIdx.x, bh = blockIdx.y, t = threadIdx.x;
  const int ul = t >> 4, e0 = (t & 15) * 8;
  const int u = ug * 8 + ul;
  const bf16* p = k_ws + ((size_t)bh*64 + u)*8192 + e0;
  float acc[8];
  #pragma unroll
  for (int j = 0; j < 8; ++j) acc[j] = 0.f;
  for (int i = 0; i < 64; ++i) {
    bf16x8 kv = *(const bf16x8*)&p[i*128];
    #pragma unroll
    for (int j = 0; j < 8; ++j) acc[j] += (float)kv[j];
  }
  float* dst = bkr_g + (size_t)bh*8192 + u*128 + e0;
  #pragma unroll
  for (int j = 0; j < 8; ++j) dst[j] = acc[j];
}

// ---------------------------------------------------------------------------
// Sinkhorn R per bh (32 blocks, 256 threads). Gumbel inner expr in fp64.
// ---------------------------------------------------------------------------
__global__ __launch_bounds__(256)
void sinkhorn_R(const float* __restrict__ bkr_g, const void* __restrict__ sort_w,
                const void* __restrict__ noise, float* __restrict__ R_buf,
                const void* __restrict__ xdet)
{
  const bool f32 = input_is_fp32(xdet);
  const int bh = blockIdx.x, h = bh & 7, tid = threadIdx.x;
  __shared__ float bkr[64*128];
  __shared__ float ew[128*64];
  __shared__ float R[64*65];

  for (int f = tid; f < 64*128; f += 256) bkr[f] = bkr_g[(size_t)bh*8192 + f];
  for (int f = tid; f < 128*64; f += 256) ew[f] = ldx(sort_w, (size_t)h*8192 + f, f32);
  __syncthreads();

  for (int f = tid; f < 64*64; f += 256) {
    const int u = f >> 6, v = f & 63;
    float s = 0.f;
    for (int e = 0; e < 128; ++e) s += bkr[u*128 + e] * ew[e*64 + v];
    s = fmaxf(s, 0.f);
    const float r  = logf(s + 1e-6f);
    const double nz = (double)ldx(noise, ((size_t)bh*64 + u)*64 + v, f32);
    const double t1 = log(nz + 1e-4);
    const double t2 = fmax(-t1 + 1e-4, 1e-30);
    const float g = (float)(-log(t2));
    R[u*65 + v] = (r + g) * (1.f / 0.75f);
  }
  __syncthreads();

  for (int it = 0; it < 5; ++it) {
    if (tid < 64) {
      float mx = -1e30f;
      for (int v = 0; v < 64; ++v) mx = fmaxf(mx, R[tid*65 + v]);
      float s = 0.f;
      for (int v = 0; v < 64; ++v) s += expf(R[tid*65 + v] - mx);
      const float l = mx + logf(s);
      for (int v = 0; v < 64; ++v) R[tid*65 + v] -= l;
    }
    __syncthreads();
    if (tid < 64) {
      float mx = -1e30f;
      for (int u = 0; u < 64; ++u) mx = fmaxf(mx, R[u*65 + tid]);
      float s = 0.f;
      for (int u = 0; u < 64; ++u) s += expf(R[u*65 + tid] - mx);
      const float l = mx + logf(s);
      for (int u = 0; u < 64; ++u) R[u*65 + tid] -= l;
    }
    __syncthreads();
  }

  for (int f = tid; f < 64*64; f += 256) {
    const int u = f >> 6, v = f & 63;
    R_buf[(size_t)bh*4096 + f] = (u > v) ? expf(R[u*65 + v]) : 0.f;
  }
}

// ---------------------------------------------------------------------------
// permute_kv: Out[bhl][u][f] = sum_v R[bh][u][v] * X[bh][v][f]  (f = 8192)
// One block = (256-f chunk, bh-local, tensor z). R as bf16 hi+lo (K=128) for
// ~fp32 weight precision. X staged into 16-f subtiles [64 v][16 f] row-major.
// B-frags via ds_read_b64_tr_b16. Contract (m156/m162): per-lane load of 8 B
// + fixed intra-16-lane permute; with lane addr = win + 8*(lane&15) BYTES the
// lane receives bf16 elems win_elems + (lane&15) + 16*j, j=0..3 (col lane&15,
// rows j of the window's 4x16 tile). Window for quad q = base + 256*q bytes
// (rows 8q..8q+3); offsets 128/1024/1152 walk rows +4 / +32 / +36.
// ---------------------------------------------------------------------------
__global__ __launch_bounds__(256)
void permute_kv(const float* __restrict__ R_buf,
                const bf16* __restrict__ Xk, const bf16* __restrict__ Xv,
                bf16* __restrict__ Ok, bf16* __restrict__ Ov, int bh0)
{
  const int tid = threadIdx.x;
  const int bhl = blockIdx.y, bh = bh0 + bhl;
  const int f0  = blockIdx.x * 256;
  const bf16* X = blockIdx.z ? Xv : Xk;
  bf16*       O = blockIdx.z ? Ov : Ok;

  __shared__ __align__(16) bf16 A_lds[64*136];    // R hi|lo, padded stride 136
  __shared__ __align__(16) bf16 X_lds[16*1048];   // 16 fgrps x [64 v][16 f]

  // stage X tile [64 v][256 f]: X_lds[fgrp][v][j] = X[v][f0 + fgrp*16 + j]
  {
    const bf16* Xg = X + (size_t)bh*524288 + f0;
    const int vb = tid >> 5, c = tid & 31;        // c: 8-f chunk
    const int dst = (c >> 1)*1048 + (c & 1)*8;
    #pragma unroll
    for (int p = 0; p < 8; ++p) {
      const int v = vb + p*8;
      *(bf16x8*)&X_lds[dst + v*16] = *(const bf16x8*)&Xg[(size_t)v*8192 + c*8];
    }
  }
  // stage R split: A[u][v]=hi(R), A[u][64+v]=lo(R)
  {
    const float* Rg = R_buf + (size_t)bh*4096;
    #pragma unroll
    for (int p = 0; p < 16; ++p) {
      const int idx = tid + p*256;
      const int uu = idx >> 6, vv = idx & 63;
      const float r = Rg[idx];
      const bf16 hi = (bf16)r;
      const float lo = r - (float)hi;
      A_lds[uu*136 + vv]      = hi;
      A_lds[uu*136 + 64 + vv] = (bf16)lo;
    }
  }
  __syncthreads();

  const int lane = tid & 63, wave = tid >> 6;
  const int fr = lane & 15, quad = lane >> 4;

  bf16x8 af[4][4];
  #pragma unroll
  for (int mt = 0; mt < 4; ++mt)
    #pragma unroll
    for (int ks = 0; ks < 4; ++ks)
      af[mt][ks] = *(const bf16x8*)&A_lds[(mt*16 + fr)*136 + ks*32 + quad*8];

  f32x4 acc[4][4];
  #pragma unroll
  for (int a = 0; a < 4; ++a)
    #pragma unroll
    for (int b = 0; b < 4; ++b) { f32x4 z = {0.f,0.f,0.f,0.f}; acc[a][b] = z; }

  #pragma unroll
  for (int nt = 0; nt < 4; ++nt) {
    const int g = wave*4 + nt;
    // per-lane addr (BYTES) = 2096*g + 256*quad + 8*fr  ->  elems: +4*fr
    const unsigned addr = (unsigned)(size_t)
        (__attribute__((address_space(3))) bf16*)&X_lds[g*1048 + quad*128 + fr*4];
    u32x2 p0, p1, p2, p3;
    asm volatile(
      "ds_read_b64_tr_b16 %0, %4\n"
      "ds_read_b64_tr_b16 %1, %4 offset:128\n"
      "ds_read_b64_tr_b16 %2, %4 offset:1024\n"
      "ds_read_b64_tr_b16 %3, %4 offset:1152\n"
      : "=&v"(p0), "=&v"(p1), "=&v"(p2), "=&v"(p3)
      : "v"(addr));
    asm volatile("s_waitcnt lgkmcnt(0)" ::: "memory");
    __builtin_amdgcn_sched_barrier(0);
    union { u32x2 u[2]; bf16x8 v; } c0, c1;
    c0.u[0] = p0; c0.u[1] = p1;               // v = quad*8 + 0..7  (v-slice 0..31)
    c1.u[0] = p2; c1.u[1] = p3;               // v-slice 32..63
    const bf16x8 b0 = c0.v, b1 = c1.v;
    #pragma unroll
    for (int mt = 0; mt < 4; ++mt) {
      acc[mt][nt] = __builtin_amdgcn_mfma_f32_16x16x32_bf16(af[mt][0], b0, acc[mt][nt], 0, 0, 0);
      acc[mt][nt] = __builtin_amdgcn_mfma_f32_16x16x32_bf16(af[mt][1], b1, acc[mt][nt], 0, 0, 0);
      acc[mt][nt] = __builtin_amdgcn_mfma_f32_16x16x32_bf16(af[mt][2], b0, acc[mt][nt], 0, 0, 0);
      acc[mt][nt] = __builtin_amdgcn_mfma_f32_16x16x32_bf16(af[mt][3], b1, acc[mt][nt], 0, 0, 0);
    }
  }

  bf16* Og = O + (size_t)bhl*524288 + f0;
  #pragma unroll
  for (int mt = 0; mt < 4; ++mt)
    #pragma unroll
    for (int nt = 0; nt < 4; ++nt)
      #pragma unroll
      for (int r = 0; r < 4; ++r)
        Og[(size_t)(mt*16 + quad*4 + r)*8192 + wave*64 + nt*16 + fr] = (bf16)acc[mt][nt][r];
}

// ---------------------------------------------------------------------------
// MFMA bucketed attention, streaming: kre/vre precomputed in global scratch.
// One block per (bh,u), 256 threads; every K/V byte read exactly once.
// ---------------------------------------------------------------------------
__global__ __launch_bounds__(256)
void attn_mfma(const bf16* __restrict__ q_ws, const bf16* __restrict__ k_ws,
               const bf16* __restrict__ vT_ws,
               const bf16* __restrict__ kre_g, const bf16* __restrict__ vre_g,
               bf16* __restrict__ aout, int bh0)
{
  const int u = blockIdx.x, bhl = blockIdx.y, bh = bh0 + bhl;
  const int tid = threadIdx.x;
  const int lane = tid & 63, wave = tid >> 6;
  const int fr = lane & 15, quad = lane >> 4;

  __shared__ __align__(16) unsigned char smem[34048];
  float* sc = (float*)smem;                 // 64 x (stride 132)
  bf16*  pA = (bf16*)smem;                  // alias, stride 136

  const size_t tileq = ((size_t)bh *64 + u) * 8192;   // q/k/vT/aout (global bh)
  const size_t tilel = ((size_t)bhl*64 + u) * 8192;   // kre/vre (half-local bh)

  {
    f32x4 dacc[4][2];
    #pragma unroll
    for (int mt = 0; mt < 4; ++mt)
      #pragma unroll
      for (int nt = 0; nt < 2; ++nt) { f32x4 z = {0.f,0.f,0.f,0.f}; dacc[mt][nt] = z; }
    #pragma unroll
    for (int ks = 0; ks < 4; ++ks) {
      bf16x8 afr[4];
      #pragma unroll
      for (int mt = 0; mt < 4; ++mt)
        afr[mt] = *(const bf16x8*)&q_ws[tileq + (size_t)(mt*16 + fr)*128 + ks*32 + quad*8];
      #pragma unroll
      for (int nt = 0; nt < 2; ++nt) {
        const int j = wave*32 + nt*16 + fr;
        bf16x8 bfr;
        if (wave < 2) bfr = *(const bf16x8*)&kre_g[tilel + (size_t)j*128 + ks*32 + quad*8];
        else          bfr = *(const bf16x8*)&k_ws[tileq + (size_t)(j - 64)*128 + ks*32 + quad*8];
        #pragma unroll
        for (int mt = 0; mt < 4; ++mt)
          dacc[mt][nt] = __builtin_amdgcn_mfma_f32_16x16x32_bf16(afr[mt], bfr, dacc[mt][nt], 0, 0, 0);
      }
    }
    #pragma unroll
    for (int mt = 0; mt < 4; ++mt)
      #pragma unroll
      for (int nt = 0; nt < 2; ++nt)
        #pragma unroll
        for (int r = 0; r < 4; ++r)
          sc[(mt*16 + quad*4 + r)*132 + wave*32 + nt*16 + fr] = dacc[mt][nt][r] * 0.03125f;
  }
  __syncthreads();

  {
    const int i = tid >> 2, jc = tid & 3;
    float pv[32];
    float mx = -1e30f;
    #pragma unroll
    for (int t = 0; t < 32; ++t) { pv[t] = sc[i*132 + jc + t*4]; mx = fmaxf(mx, pv[t]); }
    mx = fmaxf(mx, __shfl_xor(mx, 1));
    mx = fmaxf(mx, __shfl_xor(mx, 2));
    float s = 0.f;
    #pragma unroll
    for (int t = 0; t < 32; ++t) { pv[t] = expf(pv[t] - mx); s += pv[t]; }
    s += __shfl_xor(s, 1);
    s += __shfl_xor(s, 2);
    const float inv = 1.f / s;
    __syncthreads();
    #pragma unroll
    for (int t = 0; t < 32; ++t) pA[i*136 + jc + t*4] = (bf16)(pv[t] * inv);
  }
  __syncthreads();

  {
    f32x4 oacc[4][2];
    #pragma unroll
    for (int mt = 0; mt < 4; ++mt)
      #pragma unroll
      for (int nt = 0; nt < 2; ++nt) { f32x4 z = {0.f,0.f,0.f,0.f}; oacc[mt][nt] = z; }
    #pragma unroll
    for (int ks = 0; ks < 4; ++ks) {
      bf16x8 afr[4];
      #pragma unroll
      for (int mt = 0; mt < 4; ++mt)
        afr[mt] = *(const bf16x8*)&pA[(mt*16 + fr)*136 + ks*32 + quad*8];
      #pragma unroll
      for (int nt = 0; nt < 2; ++nt) {
        const int e = wave*32 + nt*16 + fr;
        bf16x8 bfr;
        if (ks < 2) bfr = *(const bf16x8*)&vre_g[tilel + (size_t)e*64 + ks*32 + quad*8];
        else        bfr = *(const bf16x8*)&vT_ws[tileq + (size_t)e*64 + (ks - 2)*32 + quad*8];
        #pragma unroll
        for (int mt = 0; mt < 4; ++mt)
          oacc[mt][nt] = __builtin_amdgcn_mfma_f32_16x16x32_bf16(afr[mt], bfr, oacc[mt][nt], 0, 0, 0);
      }
    }
    __syncthreads();
    #pragma unroll
    for (int mt = 0; mt < 4; ++mt)
      #pragma unroll
      for (int nt = 0; nt < 2; ++nt)
        #pragma unroll
        for (int r = 0; r < 4; ++r)
          pA[(mt*16 + quad*4 + r)*136 + wave*32 + nt*16 + fr] = (bf16)oacc[mt][nt][r];
  }
  __syncthreads();

  {
    const int b = bh >> 3, h = bh & 7;
    #pragma unroll
    for (int r = 0; r < 4; ++r) {
      const int f = r*2048 + tid*8;
      const int i = f >> 7, e0 = f & 127;
      bf16x8 w = *(const bf16x8*)&pA[i*136 + e0];
      *(bf16x8*)&aout[((size_t)(b*4096 + u*64 + i))*1024 + h*128 + e0] = w;
    }
  }
}

// ---------------------------------------------------------------------------
extern "C" void kernel_launch(void* const* d_in, const int* in_sizes, int n_in,
                              void* d_out, int out_size, void* d_ws, size_t ws_size,
                              hipStream_t stream)
{
  (void)in_sizes; (void)n_in; (void)out_size; (void)ws_size;
  const void* x      = d_in[0];   // (4,4096,1024)
  const void* w_qkv  = d_in[1];   // (3072,1024)
  const void* sort_w = d_in[2];   // (1,8,128,64)
  const void* w_out  = d_in[3];   // (1024,1024)
  const void* b_out  = d_in[4];   // (1024,)
  const void* noise  = d_in[5];   // (32,64,64)

  char* ws = (char*)d_ws;
  const size_t TEN = (size_t)32*64*64*128;     // 16,777,216 elements
  const size_t HEN = TEN / 2;                  // per-half kre/vre elements
  bf16* q_ws  = (bf16*)ws;
  bf16* k_ws  = q_ws + TEN;
  bf16* vT_ws = k_ws + TEN;                    // [bh][u][e][i]
  bf16* xa_ws = vT_ws + TEN;                   // x-as-bf16, later attn out (b,t,d)

  // bkr/R live in the xa tail (b=3 rows of aout, overwritten only by attn h2)
  float* bkr_g = (float*)((char*)xa_ws + (size_t)30*1024*1024);   // 1 MiB
  float* R_buf = (float*)((char*)xa_ws + (size_t)31*1024*1024);   // 512 KiB
  // d_out scratch
  bf16* wqkv_bf = (bf16*)((char*)d_out + (1536<<10));  // 6 MiB, dead after gemm1
  bf16* kre = (bf16*)d_out;                            // 16 MiB per half
  bf16* vre = kre + HEN;                               // 16 MiB per half
  bf16* wout_bf = k_ws;                                // reused after attn

  convert_to_bf16<<<8192, 256, 0, stream>>>(x, xa_ws, x);
  convert_to_bf16<<<1536, 256, 0, stream>>>(w_qkv, wqkv_bf, x);

  gemm_bt<0><<<dim3(24,128), 256, 0, stream>>>(xa_ws, wqkv_bf, nullptr,
                                               q_ws, k_ws, vT_ws, x, 16384, 3072, 1024);

  bksum<<<dim3(8,32), 128, 0, stream>>>(k_ws, bkr_g);
  sinkhorn_R<<<32, 256, 0, stream>>>(bkr_g, sort_w, noise, R_buf, x);

  // half 1: bh 0..15 (writes aout b=0,1 -> xa[0,16Mi), R stays intact)
  permute_kv<<<dim3(32,16,2), 256, 0, stream>>>(R_buf, k_ws, vT_ws, kre, vre, 0);
  attn_mfma<<<dim3(64,16), 256, 0, stream>>>(q_ws, k_ws, vT_ws, kre, vre, xa_ws, 0);
  // half 2: bh 16..31 (attn clobbers xa tail incl. bkr/R after R is consumed)
  permute_kv<<<dim3(32,16,2), 256, 0, stream>>>(R_buf, k_ws, vT_ws, kre, vre, 16);
  attn_mfma<<<dim3(64,16), 256, 0, stream>>>(q_ws, k_ws, vT_ws, kre, vre, xa_ws, 16);

  convert_to_bf16<<<512, 256, 0, stream>>>(w_out, wout_bf, x);
  gemm_bt<1><<<dim3(8,128), 256, 0, stream>>>(xa_ws, wout_bf, b_out,
                                              d_out, nullptr, nullptr, x, 16384, 1024, 1024);
}

// Round 4
// 434.334 us; speedup vs baseline: 1.3526x; 1.1034x over previous
//
#include <hip/hip_runtime.h>
#include <hip/hip_bf16.h>
#include <cstdint>
#include <cstddef>
#include <math.h>
#include <type_traits>

typedef __bf16 bf16;
typedef __bf16 bf16x4 __attribute__((ext_vector_type(4)));
typedef __bf16 bf16x8 __attribute__((ext_vector_type(8)));
typedef float  f32x4  __attribute__((ext_vector_type(4)));
typedef unsigned u32x2 __attribute__((ext_vector_type(2)));

// Shapes: B=4, T=4096, D=1024, H=8, DH=128, BUCKETS=64, BSZ=64, BH=32
// ws (128 MiB): q[bh][u][i][e] | k[bh][u][i][e] | vT[bh][u][e][i] | xa
// xa region (32 MiB): x-as-bf16 (dead after gemm1) -> bkr@+30Mi, R@+31Mi
//   (dead after 2nd permute_kv) -> aout (attn output, b-major)
// d_out scratch: wqkv_bf @+1.5Mi (dead after gemm1) -> kre 16Mi | vre 16Mi
//   per bh-half (dead before gemm2 writes d_out).
// Schedule: gemm1 -> bksum -> sinkhorn -> [permute+attn] x 2 halves -> gemm2.

__device__ inline bool input_is_fp32(const void* x) {
  const unsigned short* u = (const unsigned short*)x;
  const int lane = threadIdx.x & 63;
  const int e = (u[lane] >> 7) & 0xFF;
  return __ballot(e >= 137) != 0ULL;
}

__device__ inline float ldx(const void* p, size_t i, bool f32) {
  return f32 ? ((const float*)p)[i] : (float)((const bf16*)p)[i];
}

template<typename T>
__device__ inline bf16x8 ld8bf(const void* p, size_t i) {
  if constexpr (std::is_same<T, float>::value) {
    const f32x4* q = (const f32x4*)((const float*)p + i);
    const f32x4 a = q[0], b = q[1];
    bf16x8 r;
    r[0]=(bf16)a[0]; r[1]=(bf16)a[1]; r[2]=(bf16)a[2]; r[3]=(bf16)a[3];
    r[4]=(bf16)b[0]; r[5]=(bf16)b[1]; r[6]=(bf16)b[2]; r[7]=(bf16)b[3];
    return r;
  } else {
    return *(const bf16x8*)((const bf16*)p + i);
  }
}

// async global->LDS, 16 B per lane; LDS dest = wave-uniform base + lane*16
__device__ __forceinline__ void gload16(const void* g, void* l) {
  __builtin_amdgcn_global_load_lds(
      (__attribute__((address_space(1))) void*)g,
      (__attribute__((address_space(3))) void*)l, 16, 0, 0);
}

// ---------------------------------------------------------------------------
// dtype-flexible fp32/bf16 -> bf16 copy. One thread = 8 elements.
// ---------------------------------------------------------------------------
__global__ __launch_bounds__(256)
void convert_to_bf16(const void* __restrict__ src, bf16* __restrict__ dst,
                     const void* __restrict__ xdet) {
  const bool f32 = input_is_fp32(xdet);
  const size_t i = ((size_t)blockIdx.x * 256 + threadIdx.x) * 8;
  if (f32) *(bf16x8*)&dst[i] = ld8bf<float>(src, i);
  else     *(bf16x8*)&dst[i] = ld8bf<bf16 >(src, i);
}

// ---------------------------------------------------------------------------
// 256x256 8-phase GEMM: C[m][n] = sum_k A[m][k]*B[n][k], bf16 K-contiguous.
// BK=64 as two k-halves; LDS [buf][A/B][kh][256x32] = 128 KiB, 8 waves (2Mx4N),
// per-wave 128x64 out (acc[8][4]). Each phase: ds_read frags | stage 1 half
// (pre-swizzled global src -> linear gload_lds dest) | raw s_barrier |
// lgkmcnt(0) | setprio(1) 16 MFMA setprio(0) | counted vmcnt(8) at ph2/ph4.
// Swizzle: 16-B granule g ^= (row>>1)&3 on BOTH stage-src and ds_read (2-way).
// In-flight invariant at tile entry: [A(t)k1,B(t)k1,A(t+1)k0,B(t+1)k0] = 8.
// EPI=0: scatter into q/k ([u][i][e]) and vT ([u][e][i]). EPI=1: bias+dtype.
// ---------------------------------------------------------------------------
template<int EPI>
__global__ __launch_bounds__(512, 2)
void gemm256(const bf16* __restrict__ A, const bf16* __restrict__ Bm,
             const void* __restrict__ bias,
             void* __restrict__ C0, bf16* __restrict__ C1, bf16* __restrict__ C2,
             const void* __restrict__ xdet, int M, int N, int K)
{
  __shared__ __align__(16) bf16 lds[2][2][2][8192];   // [buf][A/B][kh][256*32]
  const int tid = threadIdx.x, wave = tid >> 6, lane = tid & 63;
  const int fr = lane & 15, quad = lane >> 4;
  const int m0 = blockIdx.y * 256, n0 = blockIdx.x * 256;
  const int wm = wave >> 2, wn = wave & 3;            // 2 x 4 wave grid
  const int gsz  = (quad ^ ((fr >> 1) & 3)) * 16;     // swizzled read granule (bytes)
  const int srow = wave * 32 + (lane >> 2);           // staging row (first of 2)
  const int sg   = ((lane & 3) ^ ((lane >> 3) & 3)) * 8; // swizzled src col (elems)
  const int NT = K >> 6;
  char* ldsb = (char*)&lds[0][0][0][0];

  auto stageA = [&](int buf, int kh, int t) {
    const bf16* s = A + (size_t)(m0 + srow) * K + t*64 + kh*32 + sg;
    char* d = ldsb + buf*65536 + kh*16384 + wave*2048;
    gload16(s, d);
    gload16(s + (size_t)16 * K, d + 1024);
  };
  auto stageB = [&](int buf, int kh, int t) {
    const bf16* s = Bm + (size_t)(n0 + srow) * K + t*64 + kh*32 + sg;
    char* d = ldsb + buf*65536 + 32768 + kh*16384 + wave*2048;
    gload16(s, d);
    gload16(s + (size_t)16 * K, d + 1024);
  };
  auto lda = [&](int c, int kh, int fi) {
    return *(const bf16x8*)(ldsb + c*65536 + kh*16384 + (wm*128 + fi*16 + fr)*64 + gsz);
  };
  auto ldb = [&](int c, int kh, int fi) {
    return *(const bf16x8*)(ldsb + c*65536 + 32768 + kh*16384 + (wn*64 + fi*16 + fr)*64 + gsz);
  };

  f32x4 acc[8][4];
  #pragma unroll
  for (int a = 0; a < 8; ++a)
    #pragma unroll
    for (int b = 0; b < 4; ++b) { f32x4 z = {0.f,0.f,0.f,0.f}; acc[a][b] = z; }

  // prologue: A0k0 B0k0 | A0k1 B0k1 | A1k0 B1k0  (12 loads; keep 8 in flight)
  stageA(0, 0, 0); stageB(0, 0, 0);
  stageA(0, 1, 0); stageB(0, 1, 0);
  stageA(1, 0, 1); stageB(1, 0, 1);
  asm volatile("s_waitcnt vmcnt(8)" ::: "memory");
  __builtin_amdgcn_s_barrier();

  #pragma unroll 1
  for (int t = 0; t < NT; ++t) {
    const int c = t & 1;
    const bool d12 = (t + 1 < NT), d34 = (t + 2 < NT);
    bf16x8 bfr[4], afr[4];

    // ---- ph1: q0,k0 ---- stage A(t+1)k1 -> buf c^1
    #pragma unroll
    for (int n = 0; n < 4; ++n) bfr[n] = ldb(c, 0, n);
    #pragma unroll
    for (int m = 0; m < 4; ++m) afr[m] = lda(c, 0, m);
    if (d12) stageA(c ^ 1, 1, t + 1);
    __builtin_amdgcn_s_barrier();
    asm volatile("s_waitcnt lgkmcnt(0)" ::: "memory");
    __builtin_amdgcn_sched_barrier(0);
    __builtin_amdgcn_s_setprio(1);
    #pragma unroll
    for (int m = 0; m < 4; ++m)
      #pragma unroll
      for (int n = 0; n < 4; ++n)
        acc[m][n] = __builtin_amdgcn_mfma_f32_16x16x32_bf16(afr[m], bfr[n], acc[m][n], 0, 0, 0);
    __builtin_amdgcn_s_setprio(0);
    __builtin_amdgcn_s_barrier();

    // ---- ph2: q1,k0 ---- stage B(t+1)k1 -> buf c^1; mid vmcnt
    #pragma unroll
    for (int m = 0; m < 4; ++m) afr[m] = lda(c, 0, 4 + m);
    if (d12) stageB(c ^ 1, 1, t + 1);
    __builtin_amdgcn_s_barrier();
    asm volatile("s_waitcnt lgkmcnt(0)" ::: "memory");
    __builtin_amdgcn_sched_barrier(0);
    __builtin_amdgcn_s_setprio(1);
    #pragma unroll
    for (int m = 0; m < 4; ++m)
      #pragma unroll
      for (int n = 0; n < 4; ++n)
        acc[4 + m][n] = __builtin_amdgcn_mfma_f32_16x16x32_bf16(afr[m], bfr[n], acc[4 + m][n], 0, 0, 0);
    __builtin_amdgcn_s_setprio(0);
    if (t < NT - 1) { asm volatile("s_waitcnt vmcnt(8)" ::: "memory"); }
    else            { asm volatile("s_waitcnt vmcnt(0)" ::: "memory"); }
    __builtin_amdgcn_s_barrier();

    // ---- ph3: q0,k1 ---- stage A(t+2)k0 -> buf c
    #pragma unroll
    for (int n = 0; n < 4; ++n) bfr[n] = ldb(c, 1, n);
    #pragma unroll
    for (int m = 0; m < 4; ++m) afr[m] = lda(c, 1, m);
    if (d34) stageA(c, 0, t + 2);
    __builtin_amdgcn_s_barrier();
    asm volatile("s_waitcnt lgkmcnt(0)" ::: "memory");
    __builtin_amdgcn_sched_barrier(0);
    __builtin_amdgcn_s_setprio(1);
    #pragma unroll
    for (int m = 0; m < 4; ++m)
      #pragma unroll
      for (int n = 0; n < 4; ++n)
        acc[m][n] = __builtin_amdgcn_mfma_f32_16x16x32_bf16(afr[m], bfr[n], acc[m][n], 0, 0, 0);
    __builtin_amdgcn_s_setprio(0);
    __builtin_amdgcn_s_barrier();

    // ---- ph4: q1,k1 ---- stage B(t+2)k0 -> buf c; boundary vmcnt
    #pragma unroll
    for (int m = 0; m < 4; ++m) afr[m] = lda(c, 1, 4 + m);
    if (d34) stageB(c, 0, t + 2);
    __builtin_amdgcn_s_barrier();
    asm volatile("s_waitcnt lgkmcnt(0)" ::: "memory");
    __builtin_amdgcn_sched_barrier(0);
    __builtin_amdgcn_s_setprio(1);
    #pragma unroll
    for (int m = 0; m < 4; ++m)
      #pragma unroll
      for (int n = 0; n < 4; ++n)
        acc[4 + m][n] = __builtin_amdgcn_mfma_f32_16x16x32_bf16(afr[m], bfr[n], acc[4 + m][n], 0, 0, 0);
    __builtin_amdgcn_s_setprio(0);
    if (t < NT - 2)       { asm volatile("s_waitcnt vmcnt(8)" ::: "memory"); }
    else if (t == NT - 2) { asm volatile("s_waitcnt vmcnt(4)" ::: "memory"); }
    __builtin_amdgcn_s_barrier();
  }

  // C/D layout: col = lane&15 (fr), row = quad*4 + reg
  if constexpr (EPI == 0) {
    const int sel = n0 >> 10;               // block-uniform (n0 mult of 256)
    const int cb  = (n0 & 1023) + wn * 64;
    #pragma unroll
    for (int im = 0; im < 8; ++im) {
      const int mrow = m0 + wm*128 + im*16 + quad*4;
      const int b = mrow >> 12, tt = mrow & 4095;
      const int u = tt >> 6, i = tt & 63;   // i..i+3 stay in-bucket
      #pragma unroll
      for (int nn = 0; nn < 4; ++nn) {
        const int cc = cb + nn*16 + fr;
        const int h = cc >> 7, e = cc & 127;
        const size_t bhu = (size_t)((b*8 + h)*64 + u);
        if (sel == 2) {                     // vT [u][e][i]: one 8-B store
          bf16x4 w;
          #pragma unroll
          for (int r = 0; r < 4; ++r) w[r] = (bf16)acc[im][nn][r];
          *(bf16x4*)&C2[(bhu*128 + e)*64 + i] = w;
        } else {                            // q/k [u][i][e]
          bf16* dst = (sel == 0) ? (bf16*)C0 : C1;
          #pragma unroll
          for (int r = 0; r < 4; ++r)
            dst[(bhu*64 + i + r)*128 + e] = (bf16)acc[im][nn][r];
        }
      }
    }
  } else {
    const bool f32o = input_is_fp32(xdet);
    #pragma unroll
    for (int im = 0; im < 8; ++im) {
      #pragma unroll
      for (int nn = 0; nn < 4; ++nn) {
        #pragma unroll
        for (int r = 0; r < 4; ++r) {
          const int m = m0 + wm*128 + im*16 + quad*4 + r;
          const int n = n0 + wn*64 + nn*16 + fr;
          const float val = acc[im][nn][r] + ldx(bias, n, f32o);
          if (f32o) ((float*)C0)[(size_t)m*N + n] = val;
          else      ((bf16*)C0)[(size_t)m*N + n] = (bf16)val;
        }
      }
    }
  }
}

// ---------------------------------------------------------------------------
// bksum: bkr[bh][u][e] = sum_i k[bh][u][i][e]. grid (8,32), 128 threads.
// ---------------------------------------------------------------------------
__global__ __launch_bounds__(128)
void bksum(const bf16* __restrict__ k_ws, float* __restrict__ bkr_g)
{
  const int ug = blockIdx.x, bh = blockIdx.y, t = threadIdx.x;
  const int ul = t >> 4, e0 = (t & 15) * 8;
  const int u = ug * 8 + ul;
  const bf16* p = k_ws + ((size_t)bh*64 + u)*8192 + e0;
  float acc[8];
  #pragma unroll
  for (int j = 0; j < 8; ++j) acc[j] = 0.f;
  for (int i = 0; i < 64; ++i) {
    bf16x8 kv = *(const bf16x8*)&p[i*128];
    #pragma unroll
    for (int j = 0; j < 8; ++j) acc[j] += (float)kv[j];
  }
  float* dst = bkr_g + (size_t)bh*8192 + u*128 + e0;
  #pragma unroll
  for (int j = 0; j < 8; ++j) dst[j] = acc[j];
}

// ---------------------------------------------------------------------------
// Sinkhorn R per bh (32 blocks, 256 threads). Gumbel inner expr in fp64.
// ---------------------------------------------------------------------------
__global__ __launch_bounds__(256)
void sinkhorn_R(const float* __restrict__ bkr_g, const void* __restrict__ sort_w,
                const void* __restrict__ noise, float* __restrict__ R_buf,
                const void* __restrict__ xdet)
{
  const bool f32 = input_is_fp32(xdet);
  const int bh = blockIdx.x, h = bh & 7, tid = threadIdx.x;
  __shared__ float bkr[64*128];
  __shared__ float ew[128*64];
  __shared__ float R[64*65];

  for (int f = tid; f < 64*128; f += 256) bkr[f] = bkr_g[(size_t)bh*8192 + f];
  for (int f = tid; f < 128*64; f += 256) ew[f] = ldx(sort_w, (size_t)h*8192 + f, f32);
  __syncthreads();

  for (int f = tid; f < 64*64; f += 256) {
    const int u = f >> 6, v = f & 63;
    float s = 0.f;
    for (int e = 0; e < 128; ++e) s += bkr[u*128 + e] * ew[e*64 + v];
    s = fmaxf(s, 0.f);
    const float r  = logf(s + 1e-6f);
    const double nz = (double)ldx(noise, ((size_t)bh*64 + u)*64 + v, f32);
    const double t1 = log(nz + 1e-4);
    const double t2 = fmax(-t1 + 1e-4, 1e-30);
    const float g = (float)(-log(t2));
    R[u*65 + v] = (r + g) * (1.f / 0.75f);
  }
  __syncthreads();

  for (int it = 0; it < 5; ++it) {
    if (tid < 64) {
      float mx = -1e30f;
      for (int v = 0; v < 64; ++v) mx = fmaxf(mx, R[tid*65 + v]);
      float s = 0.f;
      for (int v = 0; v < 64; ++v) s += expf(R[tid*65 + v] - mx);
      const float l = mx + logf(s);
      for (int v = 0; v < 64; ++v) R[tid*65 + v] -= l;
    }
    __syncthreads();
    if (tid < 64) {
      float mx = -1e30f;
      for (int u = 0; u < 64; ++u) mx = fmaxf(mx, R[u*65 + tid]);
      float s = 0.f;
      for (int u = 0; u < 64; ++u) s += expf(R[u*65 + tid] - mx);
      const float l = mx + logf(s);
      for (int u = 0; u < 64; ++u) R[u*65 + tid] -= l;
    }
    __syncthreads();
  }

  for (int f = tid; f < 64*64; f += 256) {
    const int u = f >> 6, v = f & 63;
    R_buf[(size_t)bh*4096 + f] = (u > v) ? expf(R[u*65 + v]) : 0.f;
  }
}

// ---------------------------------------------------------------------------
// permute_kv: Out[bhl][u][f] = sum_v R[bh][u][v] * X[bh][v][f]  (f = 8192)
// One block = (256-f chunk, bh-local, tensor z). R as bf16 hi+lo (K=128) for
// ~fp32 weight precision. X staged into 16-f subtiles [64 v][16 f] row-major.
// B-frags via ds_read_b64_tr_b16 (lane addr = win + 8*(lane&15) bytes).
// ---------------------------------------------------------------------------
__global__ __launch_bounds__(256)
void permute_kv(const float* __restrict__ R_buf,
                const bf16* __restrict__ Xk, const bf16* __restrict__ Xv,
                bf16* __restrict__ Ok, bf16* __restrict__ Ov, int bh0)
{
  const int tid = threadIdx.x;
  const int bhl = blockIdx.y, bh = bh0 + bhl;
  const int f0  = blockIdx.x * 256;
  const bf16* X = blockIdx.z ? Xv : Xk;
  bf16*       O = blockIdx.z ? Ov : Ok;

  __shared__ __align__(16) bf16 A_lds[64*136];    // R hi|lo, padded stride 136
  __shared__ __align__(16) bf16 X_lds[16*1048];   // 16 fgrps x [64 v][16 f]

  // stage X tile [64 v][256 f]: X_lds[fgrp][v][j] = X[v][f0 + fgrp*16 + j]
  {
    const bf16* Xg = X + (size_t)bh*524288 + f0;
    const int vb = tid >> 5, c = tid & 31;        // c: 8-f chunk
    const int dst = (c >> 1)*1048 + (c & 1)*8;
    #pragma unroll
    for (int p = 0; p < 8; ++p) {
      const int v = vb + p*8;
      *(bf16x8*)&X_lds[dst + v*16] = *(const bf16x8*)&Xg[(size_t)v*8192 + c*8];
    }
  }
  // stage R split: A[u][v]=hi(R), A[u][64+v]=lo(R)
  {
    const float* Rg = R_buf + (size_t)bh*4096;
    #pragma unroll
    for (int p = 0; p < 16; ++p) {
      const int idx = tid + p*256;
      const int uu = idx >> 6, vv = idx & 63;
      const float r = Rg[idx];
      const bf16 hi = (bf16)r;
      const float lo = r - (float)hi;
      A_lds[uu*136 + vv]      = hi;
      A_lds[uu*136 + 64 + vv] = (bf16)lo;
    }
  }
  __syncthreads();

  const int lane = tid & 63, wave = tid >> 6;
  const int fr = lane & 15, quad = lane >> 4;

  bf16x8 af[4][4];
  #pragma unroll
  for (int mt = 0; mt < 4; ++mt)
    #pragma unroll
    for (int ks = 0; ks < 4; ++ks)
      af[mt][ks] = *(const bf16x8*)&A_lds[(mt*16 + fr)*136 + ks*32 + quad*8];

  f32x4 acc[4][4];
  #pragma unroll
  for (int a = 0; a < 4; ++a)
    #pragma unroll
    for (int b = 0; b < 4; ++b) { f32x4 z = {0.f,0.f,0.f,0.f}; acc[a][b] = z; }

  #pragma unroll
  for (int nt = 0; nt < 4; ++nt) {
    const int g = wave*4 + nt;
    // per-lane addr (BYTES) = 2096*g + 256*quad + 8*fr  ->  elems: +4*fr
    const unsigned addr = (unsigned)(size_t)
        (__attribute__((address_space(3))) bf16*)&X_lds[g*1048 + quad*128 + fr*4];
    u32x2 p0, p1, p2, p3;
    asm volatile(
      "ds_read_b64_tr_b16 %0, %4\n"
      "ds_read_b64_tr_b16 %1, %4 offset:128\n"
      "ds_read_b64_tr_b16 %2, %4 offset:1024\n"
      "ds_read_b64_tr_b16 %3, %4 offset:1152\n"
      : "=&v"(p0), "=&v"(p1), "=&v"(p2), "=&v"(p3)
      : "v"(addr));
    asm volatile("s_waitcnt lgkmcnt(0)" ::: "memory");
    __builtin_amdgcn_sched_barrier(0);
    union { u32x2 u[2]; bf16x8 v; } c0, c1;
    c0.u[0] = p0; c0.u[1] = p1;               // v = quad*8 + 0..7  (v-slice 0..31)
    c1.u[0] = p2; c1.u[1] = p3;               // v-slice 32..63
    const bf16x8 b0 = c0.v, b1 = c1.v;
    #pragma unroll
    for (int mt = 0; mt < 4; ++mt) {
      acc[mt][nt] = __builtin_amdgcn_mfma_f32_16x16x32_bf16(af[mt][0], b0, acc[mt][nt], 0, 0, 0);
      acc[mt][nt] = __builtin_amdgcn_mfma_f32_16x16x32_bf16(af[mt][1], b1, acc[mt][nt], 0, 0, 0);
      acc[mt][nt] = __builtin_amdgcn_mfma_f32_16x16x32_bf16(af[mt][2], b0, acc[mt][nt], 0, 0, 0);
      acc[mt][nt] = __builtin_amdgcn_mfma_f32_16x16x32_bf16(af[mt][3], b1, acc[mt][nt], 0, 0, 0);
    }
  }

  bf16* Og = O + (size_t)bhl*524288 + f0;
  #pragma unroll
  for (int mt = 0; mt < 4; ++mt)
    #pragma unroll
    for (int nt = 0; nt < 4; ++nt)
      #pragma unroll
      for (int r = 0; r < 4; ++r)
        Og[(size_t)(mt*16 + quad*4 + r)*8192 + wave*64 + nt*16 + fr] = (bf16)acc[mt][nt][r];
}

// ---------------------------------------------------------------------------
// MFMA bucketed attention, streaming: kre/vre precomputed in global scratch.
// One block per (bh,u), 256 threads; every K/V byte read exactly once.
// ---------------------------------------------------------------------------
__global__ __launch_bounds__(256)
void attn_mfma(const bf16* __restrict__ q_ws, const bf16* __restrict__ k_ws,
               const bf16* __restrict__ vT_ws,
               const bf16* __restrict__ kre_g, const bf16* __restrict__ vre_g,
               bf16* __restrict__ aout, int bh0)
{
  const int u = blockIdx.x, bhl = blockIdx.y, bh = bh0 + bhl;
  const int tid = threadIdx.x;
  const int lane = tid & 63, wave = tid >> 6;
  const int fr = lane & 15, quad = lane >> 4;

  __shared__ __align__(16) unsigned char smem[34048];
  float* sc = (float*)smem;                 // 64 x (stride 132)
  bf16*  pA = (bf16*)smem;                  // alias, stride 136

  const size_t tileq = ((size_t)bh *64 + u) * 8192;   // q/k/vT/aout (global bh)
  const size_t tilel = ((size_t)bhl*64 + u) * 8192;   // kre/vre (half-local bh)

  {
    f32x4 dacc[4][2];
    #pragma unroll
    for (int mt = 0; mt < 4; ++mt)
      #pragma unroll
      for (int nt = 0; nt < 2; ++nt) { f32x4 z = {0.f,0.f,0.f,0.f}; dacc[mt][nt] = z; }
    #pragma unroll
    for (int ks = 0; ks < 4; ++ks) {
      bf16x8 afr[4];
      #pragma unroll
      for (int mt = 0; mt < 4; ++mt)
        afr[mt] = *(const bf16x8*)&q_ws[tileq + (size_t)(mt*16 + fr)*128 + ks*32 + quad*8];
      #pragma unroll
      for (int nt = 0; nt < 2; ++nt) {
        const int j = wave*32 + nt*16 + fr;
        bf16x8 bfr;
        if (wave < 2) bfr = *(const bf16x8*)&kre_g[tilel + (size_t)j*128 + ks*32 + quad*8];
        else          bfr = *(const bf16x8*)&k_ws[tileq + (size_t)(j - 64)*128 + ks*32 + quad*8];
        #pragma unroll
        for (int mt = 0; mt < 4; ++mt)
          dacc[mt][nt] = __builtin_amdgcn_mfma_f32_16x16x32_bf16(afr[mt], bfr, dacc[mt][nt], 0, 0, 0);
      }
    }
    #pragma unroll
    for (int mt = 0; mt < 4; ++mt)
      #pragma unroll
      for (int nt = 0; nt < 2; ++nt)
        #pragma unroll
        for (int r = 0; r < 4; ++r)
          sc[(mt*16 + quad*4 + r)*132 + wave*32 + nt*16 + fr] = dacc[mt][nt][r] * 0.03125f;
  }
  __syncthreads();

  {
    const int i = tid >> 2, jc = tid & 3;
    float pv[32];
    float mx = -1e30f;
    #pragma unroll
    for (int t = 0; t < 32; ++t) { pv[t] = sc[i*132 + jc + t*4]; mx = fmaxf(mx, pv[t]); }
    mx = fmaxf(mx, __shfl_xor(mx, 1));
    mx = fmaxf(mx, __shfl_xor(mx, 2));
    float s = 0.f;
    #pragma unroll
    for (int t = 0; t < 32; ++t) { pv[t] = expf(pv[t] - mx); s += pv[t]; }
    s += __shfl_xor(s, 1);
    s += __shfl_xor(s, 2);
    const float inv = 1.f / s;
    __syncthreads();
    #pragma unroll
    for (int t = 0; t < 32; ++t) pA[i*136 + jc + t*4] = (bf16)(pv[t] * inv);
  }
  __syncthreads();

  {
    f32x4 oacc[4][2];
    #pragma unroll
    for (int mt = 0; mt < 4; ++mt)
      #pragma unroll
      for (int nt = 0; nt < 2; ++nt) { f32x4 z = {0.f,0.f,0.f,0.f}; oacc[mt][nt] = z; }
    #pragma unroll
    for (int ks = 0; ks < 4; ++ks) {
      bf16x8 afr[4];
      #pragma unroll
      for (int mt = 0; mt < 4; ++mt)
        afr[mt] = *(const bf16x8*)&pA[(mt*16 + fr)*136 + ks*32 + quad*8];
      #pragma unroll
      for (int nt = 0; nt < 2; ++nt) {
        const int e = wave*32 + nt*16 + fr;
        bf16x8 bfr;
        if (ks < 2) bfr = *(const bf16x8*)&vre_g[tilel + (size_t)e*64 + ks*32 + quad*8];
        else        bfr = *(const bf16x8*)&vT_ws[tileq + (size_t)e*64 + (ks - 2)*32 + quad*8];
        #pragma unroll
        for (int mt = 0; mt < 4; ++mt)
          oacc[mt][nt] = __builtin_amdgcn_mfma_f32_16x16x32_bf16(afr[mt], bfr, oacc[mt][nt], 0, 0, 0);
      }
    }
    __syncthreads();
    #pragma unroll
    for (int mt = 0; mt < 4; ++mt)
      #pragma unroll
      for (int nt = 0; nt < 2; ++nt)
        #pragma unroll
        for (int r = 0; r < 4; ++r)
          pA[(mt*16 + quad*4 + r)*136 + wave*32 + nt*16 + fr] = (bf16)oacc[mt][nt][r];
  }
  __syncthreads();

  {
    const int b = bh >> 3, h = bh & 7;
    #pragma unroll
    for (int r = 0; r < 4; ++r) {
      const int f = r*2048 + tid*8;
      const int i = f >> 7, e0 = f & 127;
      bf16x8 w = *(const bf16x8*)&pA[i*136 + e0];
      *(bf16x8*)&aout[((size_t)(b*4096 + u*64 + i))*1024 + h*128 + e0] = w;
    }
  }
}

// ---------------------------------------------------------------------------
extern "C" void kernel_launch(void* const* d_in, const int* in_sizes, int n_in,
                              void* d_out, int out_size, void* d_ws, size_t ws_size,
                              hipStream_t stream)
{
  (void)in_sizes; (void)n_in; (void)out_size; (void)ws_size;
  const void* x      = d_in[0];   // (4,4096,1024)
  const void* w_qkv  = d_in[1];   // (3072,1024)
  const void* sort_w = d_in[2];   // (1,8,128,64)
  const void* w_out  = d_in[3];   // (1024,1024)
  const void* b_out  = d_in[4];   // (1024,)
  const void* noise  = d_in[5];   // (32,64,64)

  char* ws = (char*)d_ws;
  const size_t TEN = (size_t)32*64*64*128;     // 16,777,216 elements
  const size_t HEN = TEN / 2;                  // per-half kre/vre elements
  bf16* q_ws  = (bf16*)ws;
  bf16* k_ws  = q_ws + TEN;
  bf16* vT_ws = k_ws + TEN;                    // [bh][u][e][i]
  bf16* xa_ws = vT_ws + TEN;                   // x-as-bf16, later attn out (b,t,d)

  // bkr/R live in the xa tail (b=3 rows of aout, overwritten only by attn h2)
  float* bkr_g = (float*)((char*)xa_ws + (size_t)30*1024*1024);   // 1 MiB
  float* R_buf = (float*)((char*)xa_ws + (size_t)31*1024*1024);   // 512 KiB
  // d_out scratch
  bf16* wqkv_bf = (bf16*)((char*)d_out + (1536<<10));  // 6 MiB, dead after gemm1
  bf16* kre = (bf16*)d_out;                            // 16 MiB per half
  bf16* vre = kre + HEN;                               // 16 MiB per half
  bf16* wout_bf = k_ws;                                // reused after attn

  convert_to_bf16<<<8192, 256, 0, stream>>>(x, xa_ws, x);
  convert_to_bf16<<<1536, 256, 0, stream>>>(w_qkv, wqkv_bf, x);

  gemm256<0><<<dim3(12,64), 512, 0, stream>>>(xa_ws, wqkv_bf, nullptr,
                                              q_ws, k_ws, vT_ws, x, 16384, 3072, 1024);

  bksum<<<dim3(8,32), 128, 0, stream>>>(k_ws, bkr_g);
  sinkhorn_R<<<32, 256, 0, stream>>>(bkr_g, sort_w, noise, R_buf, x);

  // half 1: bh 0..15 (writes aout b=0,1 -> xa[0,16Mi), R stays intact)
  permute_kv<<<dim3(32,16,2), 256, 0, stream>>>(R_buf, k_ws, vT_ws, kre, vre, 0);
  attn_mfma<<<dim3(64,16), 256, 0, stream>>>(q_ws, k_ws, vT_ws, kre, vre, xa_ws, 0);
  // half 2: bh 16..31 (attn clobbers xa tail incl. bkr/R after R is consumed)
  permute_kv<<<dim3(32,16,2), 256, 0, stream>>>(R_buf, k_ws, vT_ws, kre, vre, 16);
  attn_mfma<<<dim3(64,16), 256, 0, stream>>>(q_ws, k_ws, vT_ws, kre, vre, xa_ws, 16);

  convert_to_bf16<<<512, 256, 0, stream>>>(w_out, wout_bf, x);
  gemm256<1><<<dim3(4,64), 512, 0, stream>>>(xa_ws, wout_bf, b_out,
                                             d_out, nullptr, nullptr, x, 16384, 1024, 1024);
}

// Round 5
// 430.614 us; speedup vs baseline: 1.3642x; 1.0086x over previous
//
#include <hip/hip_runtime.h>
#include <hip/hip_bf16.h>
#include <cstdint>
#include <cstddef>
#include <math.h>
#include <type_traits>

typedef __bf16 bf16;
typedef __bf16 bf16x4 __attribute__((ext_vector_type(4)));
typedef __bf16 bf16x8 __attribute__((ext_vector_type(8)));
typedef float  f32x4  __attribute__((ext_vector_type(4)));
typedef unsigned u32x2 __attribute__((ext_vector_type(2)));

// Shapes: B=4, T=4096, D=1024, H=8, DH=128, BUCKETS=64, BSZ=64, BH=32
// ws (128 MiB): q[bh][u][i][e] | k[bh][u][i][e] | vT[bh][u][e][i] | xa
// xa region (32 MiB): x-as-bf16 (dead after gemm1) -> bkr@+30Mi, R@+31Mi
//   (dead after 2nd permute_kv) -> aout (attn output, b-major)
// d_out scratch: wqkv_bf @+1.5Mi (dead after gemm1) -> kre 16Mi | vre 16Mi
//   per bh-half (dead before gemm2 writes d_out).
// Schedule: gemm1 -> bksum -> sinkhorn -> [permute+attn] x 2 halves -> gemm2.

__device__ inline bool input_is_fp32(const void* x) {
  const unsigned short* u = (const unsigned short*)x;
  const int lane = threadIdx.x & 63;
  const int e = (u[lane] >> 7) & 0xFF;
  return __ballot(e >= 137) != 0ULL;
}

__device__ inline float ldx(const void* p, size_t i, bool f32) {
  return f32 ? ((const float*)p)[i] : (float)((const bf16*)p)[i];
}

template<typename T>
__device__ inline bf16x8 ld8bf(const void* p, size_t i) {
  if constexpr (std::is_same<T, float>::value) {
    const f32x4* q = (const f32x4*)((const float*)p + i);
    const f32x4 a = q[0], b = q[1];
    bf16x8 r;
    r[0]=(bf16)a[0]; r[1]=(bf16)a[1]; r[2]=(bf16)a[2]; r[3]=(bf16)a[3];
    r[4]=(bf16)b[0]; r[5]=(bf16)b[1]; r[6]=(bf16)b[2]; r[7]=(bf16)b[3];
    return r;
  } else {
    return *(const bf16x8*)((const bf16*)p + i);
  }
}

// async global->LDS, 16 B per lane; LDS dest = wave-uniform base + lane*16
__device__ __forceinline__ void gload16(const void* g, void* l) {
  __builtin_amdgcn_global_load_lds(
      (__attribute__((address_space(1))) void*)g,
      (__attribute__((address_space(3))) void*)l, 16, 0, 0);
}

// ---------------------------------------------------------------------------
// dtype-flexible fp32/bf16 -> bf16 copy. One thread = 8 elements.
// ---------------------------------------------------------------------------
__global__ __launch_bounds__(256)
void convert_to_bf16(const void* __restrict__ src, bf16* __restrict__ dst,
                     const void* __restrict__ xdet) {
  const bool f32 = input_is_fp32(xdet);
  const size_t i = ((size_t)blockIdx.x * 256 + threadIdx.x) * 8;
  if (f32) *(bf16x8*)&dst[i] = ld8bf<float>(src, i);
  else     *(bf16x8*)&dst[i] = ld8bf<bf16 >(src, i);
}

// merged x + wqkv convert (one launch): blocks [0,8192) -> s1, [8192,9728) -> s2
__global__ __launch_bounds__(256)
void convert_pair(const void* __restrict__ s1, bf16* __restrict__ d1,
                  const void* __restrict__ s2, bf16* __restrict__ d2,
                  const void* __restrict__ xdet) {
  const bool f32 = input_is_fp32(xdet);
  const size_t b = blockIdx.x;
  if (b < 8192) {
    const size_t i = (b*256 + threadIdx.x) * 8;
    if (f32) *(bf16x8*)&d1[i] = ld8bf<float>(s1, i);
    else     *(bf16x8*)&d1[i] = ld8bf<bf16 >(s1, i);
  } else {
    const size_t i = ((b - 8192)*256 + threadIdx.x) * 8;
    if (f32) *(bf16x8*)&d2[i] = ld8bf<float>(s2, i);
    else     *(bf16x8*)&d2[i] = ld8bf<bf16 >(s2, i);
  }
}

// ---------------------------------------------------------------------------
// 256x256 8-phase GEMM: C[m][n] = sum_k A[m][k]*B[n][k], bf16 K-contiguous.
// BK=64 as two k-halves; LDS [buf][A/B][kh][256x32] = 128 KiB, 8 waves (2Mx4N),
// per-wave 128x64 out (acc[8][4]). Counted vmcnt(8) at ph2/ph4, never 0 until
// tail. XCD-bijective blockIdx swizzle (nwg%8==0 for both call sites).
// Swizzle: 16-B granule g ^= (row>>1)&3 on BOTH stage-src and ds_read (0 conf).
// EPI=0: scatter into q/k ([u][i][e]) and vT ([u][e][i]). EPI=1: bias+dtype.
// ---------------------------------------------------------------------------
template<int EPI>
__global__ __launch_bounds__(512, 2)
void gemm256(const bf16* __restrict__ A, const bf16* __restrict__ Bm,
             const void* __restrict__ bias,
             void* __restrict__ C0, bf16* __restrict__ C1, bf16* __restrict__ C2,
             const void* __restrict__ xdet, int M, int N, int K)
{
  __shared__ __align__(16) bf16 lds[2][2][2][8192];   // [buf][A/B][kh][256*32]
  const int tid = threadIdx.x, wave = tid >> 6, lane = tid & 63;
  const int fr = lane & 15, quad = lane >> 4;
  // XCD swizzle: orig bid b -> XCD b%8; logical tile = (b%8)*cpx + b/8
  const int nwg = gridDim.x * gridDim.y;
  const int cpx = nwg >> 3;
  const int bid = blockIdx.y * gridDim.x + blockIdx.x;
  const int swz = (bid & 7) * cpx + (bid >> 3);
  const int m0 = (swz / gridDim.x) * 256, n0 = (swz % gridDim.x) * 256;
  const int wm = wave >> 2, wn = wave & 3;            // 2 x 4 wave grid
  const int gsz  = (quad ^ ((fr >> 1) & 3)) * 16;     // swizzled read granule (bytes)
  const int srow = wave * 32 + (lane >> 2);           // staging row (first of 2)
  const int sg   = ((lane & 3) ^ ((lane >> 3) & 3)) * 8; // swizzled src col (elems)
  const int NT = K >> 6;
  char* ldsb = (char*)&lds[0][0][0][0];

  auto stageA = [&](int buf, int kh, int t) {
    const bf16* s = A + (size_t)(m0 + srow) * K + t*64 + kh*32 + sg;
    char* d = ldsb + buf*65536 + kh*16384 + wave*2048;
    gload16(s, d);
    gload16(s + (size_t)16 * K, d + 1024);
  };
  auto stageB = [&](int buf, int kh, int t) {
    const bf16* s = Bm + (size_t)(n0 + srow) * K + t*64 + kh*32 + sg;
    char* d = ldsb + buf*65536 + 32768 + kh*16384 + wave*2048;
    gload16(s, d);
    gload16(s + (size_t)16 * K, d + 1024);
  };
  auto lda = [&](int c, int kh, int fi) {
    return *(const bf16x8*)(ldsb + c*65536 + kh*16384 + (wm*128 + fi*16 + fr)*64 + gsz);
  };
  auto ldb = [&](int c, int kh, int fi) {
    return *(const bf16x8*)(ldsb + c*65536 + 32768 + kh*16384 + (wn*64 + fi*16 + fr)*64 + gsz);
  };

  f32x4 acc[8][4];
  #pragma unroll
  for (int a = 0; a < 8; ++a)
    #pragma unroll
    for (int b = 0; b < 4; ++b) { f32x4 z = {0.f,0.f,0.f,0.f}; acc[a][b] = z; }

  // prologue: A0k0 B0k0 | A0k1 B0k1 | A1k0 B1k0  (12 loads; keep 8 in flight)
  stageA(0, 0, 0); stageB(0, 0, 0);
  stageA(0, 1, 0); stageB(0, 1, 0);
  stageA(1, 0, 1); stageB(1, 0, 1);
  asm volatile("s_waitcnt vmcnt(8)" ::: "memory");
  __builtin_amdgcn_s_barrier();

  #pragma unroll 1
  for (int t = 0; t < NT; ++t) {
    const int c = t & 1;
    const bool d12 = (t + 1 < NT), d34 = (t + 2 < NT);
    bf16x8 bfr[4], afr[4];

    // ---- ph1: q0,k0 ---- stage A(t+1)k1 -> buf c^1
    #pragma unroll
    for (int n = 0; n < 4; ++n) bfr[n] = ldb(c, 0, n);
    #pragma unroll
    for (int m = 0; m < 4; ++m) afr[m] = lda(c, 0, m);
    if (d12) stageA(c ^ 1, 1, t + 1);
    __builtin_amdgcn_s_barrier();
    asm volatile("s_waitcnt lgkmcnt(0)" ::: "memory");
    __builtin_amdgcn_sched_barrier(0);
    __builtin_amdgcn_s_setprio(1);
    #pragma unroll
    for (int m = 0; m < 4; ++m)
      #pragma unroll
      for (int n = 0; n < 4; ++n)
        acc[m][n] = __builtin_amdgcn_mfma_f32_16x16x32_bf16(afr[m], bfr[n], acc[m][n], 0, 0, 0);
    __builtin_amdgcn_s_setprio(0);
    __builtin_amdgcn_s_barrier();

    // ---- ph2: q1,k0 ---- stage B(t+1)k1 -> buf c^1; mid vmcnt
    #pragma unroll
    for (int m = 0; m < 4; ++m) afr[m] = lda(c, 0, 4 + m);
    if (d12) stageB(c ^ 1, 1, t + 1);
    __builtin_amdgcn_s_barrier();
    asm volatile("s_waitcnt lgkmcnt(0)" ::: "memory");
    __builtin_amdgcn_sched_barrier(0);
    __builtin_amdgcn_s_setprio(1);
    #pragma unroll
    for (int m = 0; m < 4; ++m)
      #pragma unroll
      for (int n = 0; n < 4; ++n)
        acc[4 + m][n] = __builtin_amdgcn_mfma_f32_16x16x32_bf16(afr[m], bfr[n], acc[4 + m][n], 0, 0, 0);
    __builtin_amdgcn_s_setprio(0);
    if (t < NT - 1) { asm volatile("s_waitcnt vmcnt(8)" ::: "memory"); }
    else            { asm volatile("s_waitcnt vmcnt(0)" ::: "memory"); }
    __builtin_amdgcn_s_barrier();

    // ---- ph3: q0,k1 ---- stage A(t+2)k0 -> buf c
    #pragma unroll
    for (int n = 0; n < 4; ++n) bfr[n] = ldb(c, 1, n);
    #pragma unroll
    for (int m = 0; m < 4; ++m) afr[m] = lda(c, 1, m);
    if (d34) stageA(c, 0, t + 2);
    __builtin_amdgcn_s_barrier();
    asm volatile("s_waitcnt lgkmcnt(0)" ::: "memory");
    __builtin_amdgcn_sched_barrier(0);
    __builtin_amdgcn_s_setprio(1);
    #pragma unroll
    for (int m = 0; m < 4; ++m)
      #pragma unroll
      for (int n = 0; n < 4; ++n)
        acc[m][n] = __builtin_amdgcn_mfma_f32_16x16x32_bf16(afr[m], bfr[n], acc[m][n], 0, 0, 0);
    __builtin_amdgcn_s_setprio(0);
    __builtin_amdgcn_s_barrier();

    // ---- ph4: q1,k1 ---- stage B(t+2)k0 -> buf c; boundary vmcnt
    #pragma unroll
    for (int m = 0; m < 4; ++m) afr[m] = lda(c, 1, 4 + m);
    if (d34) stageB(c, 0, t + 2);
    __builtin_amdgcn_s_barrier();
    asm volatile("s_waitcnt lgkmcnt(0)" ::: "memory");
    __builtin_amdgcn_sched_barrier(0);
    __builtin_amdgcn_s_setprio(1);
    #pragma unroll
    for (int m = 0; m < 4; ++m)
      #pragma unroll
      for (int n = 0; n < 4; ++n)
        acc[4 + m][n] = __builtin_amdgcn_mfma_f32_16x16x32_bf16(afr[m], bfr[n], acc[4 + m][n], 0, 0, 0);
    __builtin_amdgcn_s_setprio(0);
    if (t < NT - 2)       { asm volatile("s_waitcnt vmcnt(8)" ::: "memory"); }
    else if (t == NT - 2) { asm volatile("s_waitcnt vmcnt(4)" ::: "memory"); }
    __builtin_amdgcn_s_barrier();
  }

  // C/D layout: col = lane&15 (fr), row = quad*4 + reg
  if constexpr (EPI == 0) {
    const int sel = n0 >> 10;               // block-uniform (n0 mult of 256)
    const int cb  = (n0 & 1023) + wn * 64;
    #pragma unroll
    for (int im = 0; im < 8; ++im) {
      const int mrow = m0 + wm*128 + im*16 + quad*4;
      const int b = mrow >> 12, tt = mrow & 4095;
      const int u = tt >> 6, i = tt & 63;   // i..i+3 stay in-bucket
      #pragma unroll
      for (int nn = 0; nn < 4; ++nn) {
        const int cc = cb + nn*16 + fr;
        const int h = cc >> 7, e = cc & 127;
        const size_t bhu = (size_t)((b*8 + h)*64 + u);
        if (sel == 2) {                     // vT [u][e][i]: one 8-B store
          bf16x4 w;
          #pragma unroll
          for (int r = 0; r < 4; ++r) w[r] = (bf16)acc[im][nn][r];
          *(bf16x4*)&C2[(bhu*128 + e)*64 + i] = w;
        } else {                            // q/k [u][i][e]
          bf16* dst = (sel == 0) ? (bf16*)C0 : C1;
          #pragma unroll
          for (int r = 0; r < 4; ++r)
            dst[(bhu*64 + i + r)*128 + e] = (bf16)acc[im][nn][r];
        }
      }
    }
  } else {
    const bool f32o = input_is_fp32(xdet);
    #pragma unroll
    for (int im = 0; im < 8; ++im) {
      #pragma unroll
      for (int nn = 0; nn < 4; ++nn) {
        #pragma unroll
        for (int r = 0; r < 4; ++r) {
          const int m = m0 + wm*128 + im*16 + quad*4 + r;
          const int n = n0 + wn*64 + nn*16 + fr;
          const float val = acc[im][nn][r] + ldx(bias, n, f32o);
          if (f32o) ((float*)C0)[(size_t)m*N + n] = val;
          else      ((bf16*)C0)[(size_t)m*N + n] = (bf16)val;
        }
      }
    }
  }
}

// ---------------------------------------------------------------------------
// bksum: bkr[bh][u][e] = sum_i k[bh][u][i][e]. grid (8,32), 128 threads.
// ---------------------------------------------------------------------------
__global__ __launch_bounds__(128)
void bksum(const bf16* __restrict__ k_ws, float* __restrict__ bkr_g)
{
  const int ug = blockIdx.x, bh = blockIdx.y, t = threadIdx.x;
  const int ul = t >> 4, e0 = (t & 15) * 8;
  const int u = ug * 8 + ul;
  const bf16* p = k_ws + ((size_t)bh*64 + u)*8192 + e0;
  float acc[8];
  #pragma unroll
  for (int j = 0; j < 8; ++j) acc[j] = 0.f;
  for (int i = 0; i < 64; ++i) {
    bf16x8 kv = *(const bf16x8*)&p[i*128];
    #pragma unroll
    for (int j = 0; j < 8; ++j) acc[j] += (float)kv[j];
  }
  float* dst = bkr_g + (size_t)bh*8192 + u*128 + e0;
  #pragma unroll
  for (int j = 0; j < 8; ++j) dst[j] = acc[j];
}

// ---------------------------------------------------------------------------
// Sinkhorn R per bh (32 blocks, 256 threads). Gumbel inner expr in fp64.
// LSE phases parallelized: 4 threads/row (or col) + shfl_xor(1,2) reduce.
// ---------------------------------------------------------------------------
__global__ __launch_bounds__(256)
void sinkhorn_R(const float* __restrict__ bkr_g, const void* __restrict__ sort_w,
                const void* __restrict__ noise, float* __restrict__ R_buf,
                const void* __restrict__ xdet)
{
  const bool f32 = input_is_fp32(xdet);
  const int bh = blockIdx.x, h = bh & 7, tid = threadIdx.x;
  __shared__ float bkr[64*128];
  __shared__ float ew[128*64];
  __shared__ float R[64*65];

  for (int f = tid; f < 64*128; f += 256) bkr[f] = bkr_g[(size_t)bh*8192 + f];
  for (int f = tid; f < 128*64; f += 256) ew[f] = ldx(sort_w, (size_t)h*8192 + f, f32);
  __syncthreads();

  for (int f = tid; f < 64*64; f += 256) {
    const int u = f >> 6, v = f & 63;
    float s = 0.f;
    for (int e = 0; e < 128; ++e) s += bkr[u*128 + e] * ew[e*64 + v];
    s = fmaxf(s, 0.f);
    const float r  = logf(s + 1e-6f);
    const double nz = (double)ldx(noise, ((size_t)bh*64 + u)*64 + v, f32);
    const double t1 = log(nz + 1e-4);
    const double t2 = fmax(-t1 + 1e-4, 1e-30);
    const float g = (float)(-log(t2));
    R[u*65 + v] = (r + g) * (1.f / 0.75f);
  }
  __syncthreads();

  const int rc = tid >> 2, c4 = tid & 3;   // 4 lanes per row/col (same quad)
  for (int it = 0; it < 5; ++it) {
    {  // row LSE
      float mx = -1e30f;
      for (int v = c4; v < 64; v += 4) mx = fmaxf(mx, R[rc*65 + v]);
      mx = fmaxf(mx, __shfl_xor(mx, 1));
      mx = fmaxf(mx, __shfl_xor(mx, 2));
      float s = 0.f;
      for (int v = c4; v < 64; v += 4) s += expf(R[rc*65 + v] - mx);
      s += __shfl_xor(s, 1);
      s += __shfl_xor(s, 2);
      const float l = mx + logf(s);
      for (int v = c4; v < 64; v += 4) R[rc*65 + v] -= l;
    }
    __syncthreads();
    {  // col LSE
      float mx = -1e30f;
      for (int u = c4; u < 64; u += 4) mx = fmaxf(mx, R[u*65 + rc]);
      mx = fmaxf(mx, __shfl_xor(mx, 1));
      mx = fmaxf(mx, __shfl_xor(mx, 2));
      float s = 0.f;
      for (int u = c4; u < 64; u += 4) s += expf(R[u*65 + rc] - mx);
      s += __shfl_xor(s, 1);
      s += __shfl_xor(s, 2);
      const float l = mx + logf(s);
      for (int u = c4; u < 64; u += 4) R[u*65 + rc] -= l;
    }
    __syncthreads();
  }

  for (int f = tid; f < 64*64; f += 256) {
    const int u = f >> 6, v = f & 63;
    R_buf[(size_t)bh*4096 + f] = (u > v) ? expf(R[u*65 + v]) : 0.f;
  }
}

// ---------------------------------------------------------------------------
// permute_kv: Out[bhl][u][f] = sum_v R[bh][u][v] * X[bh][v][f]  (f = 8192)
// One block = (256-f chunk, bh-local, tensor z). R as bf16 hi+lo (K=128) for
// ~fp32 weight precision. X staged into 16-f subtiles [64 v][16 f] row-major.
// B-frags via ds_read_b64_tr_b16 (lane addr = win + 8*(lane&15) bytes).
// ---------------------------------------------------------------------------
__global__ __launch_bounds__(256)
void permute_kv(const float* __restrict__ R_buf,
                const bf16* __restrict__ Xk, const bf16* __restrict__ Xv,
                bf16* __restrict__ Ok, bf16* __restrict__ Ov, int bh0)
{
  const int tid = threadIdx.x;
  const int bhl = blockIdx.y, bh = bh0 + bhl;
  const int f0  = blockIdx.x * 256;
  const bf16* X = blockIdx.z ? Xv : Xk;
  bf16*       O = blockIdx.z ? Ov : Ok;

  __shared__ __align__(16) bf16 A_lds[64*136];    // R hi|lo, padded stride 136
  __shared__ __align__(16) bf16 X_lds[16*1048];   // 16 fgrps x [64 v][16 f]

  // stage X tile [64 v][256 f]: X_lds[fgrp][v][j] = X[v][f0 + fgrp*16 + j]
  {
    const bf16* Xg = X + (size_t)bh*524288 + f0;
    const int vb = tid >> 5, c = tid & 31;        // c: 8-f chunk
    const int dst = (c >> 1)*1048 + (c & 1)*8;
    #pragma unroll
    for (int p = 0; p < 8; ++p) {
      const int v = vb + p*8;
      *(bf16x8*)&X_lds[dst + v*16] = *(const bf16x8*)&Xg[(size_t)v*8192 + c*8];
    }
  }
  // stage R split: A[u][v]=hi(R), A[u][64+v]=lo(R)
  {
    const float* Rg = R_buf + (size_t)bh*4096;
    #pragma unroll
    for (int p = 0; p < 16; ++p) {
      const int idx = tid + p*256;
      const int uu = idx >> 6, vv = idx & 63;
      const float r = Rg[idx];
      const bf16 hi = (bf16)r;
      const float lo = r - (float)hi;
      A_lds[uu*136 + vv]      = hi;
      A_lds[uu*136 + 64 + vv] = (bf16)lo;
    }
  }
  __syncthreads();

  const int lane = tid & 63, wave = tid >> 6;
  const int fr = lane & 15, quad = lane >> 4;

  bf16x8 af[4][4];
  #pragma unroll
  for (int mt = 0; mt < 4; ++mt)
    #pragma unroll
    for (int ks = 0; ks < 4; ++ks)
      af[mt][ks] = *(const bf16x8*)&A_lds[(mt*16 + fr)*136 + ks*32 + quad*8];

  f32x4 acc[4][4];
  #pragma unroll
  for (int a = 0; a < 4; ++a)
    #pragma unroll
    for (int b = 0; b < 4; ++b) { f32x4 z = {0.f,0.f,0.f,0.f}; acc[a][b] = z; }

  #pragma unroll
  for (int nt = 0; nt < 4; ++nt) {
    const int g = wave*4 + nt;
    // per-lane addr (BYTES) = 2096*g + 256*quad + 8*fr  ->  elems: +4*fr
    const unsigned addr = (unsigned)(size_t)
        (__attribute__((address_space(3))) bf16*)&X_lds[g*1048 + quad*128 + fr*4];
    u32x2 p0, p1, p2, p3;
    asm volatile(
      "ds_read_b64_tr_b16 %0, %4\n"
      "ds_read_b64_tr_b16 %1, %4 offset:128\n"
      "ds_read_b64_tr_b16 %2, %4 offset:1024\n"
      "ds_read_b64_tr_b16 %3, %4 offset:1152\n"
      : "=&v"(p0), "=&v"(p1), "=&v"(p2), "=&v"(p3)
      : "v"(addr));
    asm volatile("s_waitcnt lgkmcnt(0)" ::: "memory");
    __builtin_amdgcn_sched_barrier(0);
    union { u32x2 u[2]; bf16x8 v; } c0, c1;
    c0.u[0] = p0; c0.u[1] = p1;               // v = quad*8 + 0..7  (v-slice 0..31)
    c1.u[0] = p2; c1.u[1] = p3;               // v-slice 32..63
    const bf16x8 b0 = c0.v, b1 = c1.v;
    #pragma unroll
    for (int mt = 0; mt < 4; ++mt) {
      acc[mt][nt] = __builtin_amdgcn_mfma_f32_16x16x32_bf16(af[mt][0], b0, acc[mt][nt], 0, 0, 0);
      acc[mt][nt] = __builtin_amdgcn_mfma_f32_16x16x32_bf16(af[mt][1], b1, acc[mt][nt], 0, 0, 0);
      acc[mt][nt] = __builtin_amdgcn_mfma_f32_16x16x32_bf16(af[mt][2], b0, acc[mt][nt], 0, 0, 0);
      acc[mt][nt] = __builtin_amdgcn_mfma_f32_16x16x32_bf16(af[mt][3], b1, acc[mt][nt], 0, 0, 0);
    }
  }

  bf16* Og = O + (size_t)bhl*524288 + f0;
  #pragma unroll
  for (int mt = 0; mt < 4; ++mt)
    #pragma unroll
    for (int nt = 0; nt < 4; ++nt)
      #pragma unroll
      for (int r = 0; r < 4; ++r)
        Og[(size_t)(mt*16 + quad*4 + r)*8192 + wave*64 + nt*16 + fr] = (bf16)acc[mt][nt][r];
}

// ---------------------------------------------------------------------------
// MFMA bucketed attention, streaming: kre/vre precomputed in global scratch.
// One block per (bh,u), 256 threads; every K/V byte read exactly once.
// T14: cold vT PV-fragments issued BEFORE dots so HBM latency hides under
// QK^T + softmax (vre is L2/L3-warm from permute; not prefetched).
// ---------------------------------------------------------------------------
__global__ __launch_bounds__(256)
void attn_mfma(const bf16* __restrict__ q_ws, const bf16* __restrict__ k_ws,
               const bf16* __restrict__ vT_ws,
               const bf16* __restrict__ kre_g, const bf16* __restrict__ vre_g,
               bf16* __restrict__ aout, int bh0)
{
  const int u = blockIdx.x, bhl = blockIdx.y, bh = bh0 + bhl;
  const int tid = threadIdx.x;
  const int lane = tid & 63, wave = tid >> 6;
  const int fr = lane & 15, quad = lane >> 4;

  __shared__ __align__(16) unsigned char smem[34048];
  float* sc = (float*)smem;                 // 64 x (stride 132)
  bf16*  pA = (bf16*)smem;                  // alias, stride 136

  const size_t tileq = ((size_t)bh *64 + u) * 8192;   // q/k/vT/aout (global bh)
  const size_t tilel = ((size_t)bhl*64 + u) * 8192;   // kre/vre (half-local bh)

  // T14 prefetch: vT frags for PV (ks = 2,3), 16 VGPR held across dots+softmax
  bf16x8 pvT[2][2];
  #pragma unroll
  for (int nt = 0; nt < 2; ++nt) {
    const int e = wave*32 + nt*16 + fr;
    #pragma unroll
    for (int k2 = 0; k2 < 2; ++k2)
      pvT[nt][k2] = *(const bf16x8*)&vT_ws[tileq + (size_t)e*64 + k2*32 + quad*8];
  }

  {
    f32x4 dacc[4][2];
    #pragma unroll
    for (int mt = 0; mt < 4; ++mt)
      #pragma unroll
      for (int nt = 0; nt < 2; ++nt) { f32x4 z = {0.f,0.f,0.f,0.f}; dacc[mt][nt] = z; }
    #pragma unroll
    for (int ks = 0; ks < 4; ++ks) {
      bf16x8 afr[4];
      #pragma unroll
      for (int mt = 0; mt < 4; ++mt)
        afr[mt] = *(const bf16x8*)&q_ws[tileq + (size_t)(mt*16 + fr)*128 + ks*32 + quad*8];
      #pragma unroll
      for (int nt = 0; nt < 2; ++nt) {
        const int j = wave*32 + nt*16 + fr;
        bf16x8 bfr;
        if (wave < 2) bfr = *(const bf16x8*)&kre_g[tilel + (size_t)j*128 + ks*32 + quad*8];
        else          bfr = *(const bf16x8*)&k_ws[tileq + (size_t)(j - 64)*128 + ks*32 + quad*8];
        #pragma unroll
        for (int mt = 0; mt < 4; ++mt)
          dacc[mt][nt] = __builtin_amdgcn_mfma_f32_16x16x32_bf16(afr[mt], bfr, dacc[mt][nt], 0, 0, 0);
      }
    }
    #pragma unroll
    for (int mt = 0; mt < 4; ++mt)
      #pragma unroll
      for (int nt = 0; nt < 2; ++nt)
        #pragma unroll
        for (int r = 0; r < 4; ++r)
          sc[(mt*16 + quad*4 + r)*132 + wave*32 + nt*16 + fr] = dacc[mt][nt][r] * 0.03125f;
  }
  __syncthreads();

  {
    const int i = tid >> 2, jc = tid & 3;
    float pv[32];
    float mx = -1e30f;
    #pragma unroll
    for (int t = 0; t < 32; ++t) { pv[t] = sc[i*132 + jc + t*4]; mx = fmaxf(mx, pv[t]); }
    mx = fmaxf(mx, __shfl_xor(mx, 1));
    mx = fmaxf(mx, __shfl_xor(mx, 2));
    float s = 0.f;
    #pragma unroll
    for (int t = 0; t < 32; ++t) { pv[t] = expf(pv[t] - mx); s += pv[t]; }
    s += __shfl_xor(s, 1);
    s += __shfl_xor(s, 2);
    const float inv = 1.f / s;
    __syncthreads();
    #pragma unroll
    for (int t = 0; t < 32; ++t) pA[i*136 + jc + t*4] = (bf16)(pv[t] * inv);
  }
  __syncthreads();

  {
    f32x4 oacc[4][2];
    #pragma unroll
    for (int mt = 0; mt < 4; ++mt)
      #pragma unroll
      for (int nt = 0; nt < 2; ++nt) { f32x4 z = {0.f,0.f,0.f,0.f}; oacc[mt][nt] = z; }
    #pragma unroll
    for (int ks = 0; ks < 4; ++ks) {
      bf16x8 afr[4];
      #pragma unroll
      for (int mt = 0; mt < 4; ++mt)
        afr[mt] = *(const bf16x8*)&pA[(mt*16 + fr)*136 + ks*32 + quad*8];
      #pragma unroll
      for (int nt = 0; nt < 2; ++nt) {
        bf16x8 bfr;
        if (ks < 2) {
          const int e = wave*32 + nt*16 + fr;
          bfr = *(const bf16x8*)&vre_g[tilel + (size_t)e*64 + ks*32 + quad*8];
        } else {
          bfr = pvT[nt][ks - 2];
        }
        #pragma unroll
        for (int mt = 0; mt < 4; ++mt)
          oacc[mt][nt] = __builtin_amdgcn_mfma_f32_16x16x32_bf16(afr[mt], bfr, oacc[mt][nt], 0, 0, 0);
      }
    }
    __syncthreads();
    #pragma unroll
    for (int mt = 0; mt < 4; ++mt)
      #pragma unroll
      for (int nt = 0; nt < 2; ++nt)
        #pragma unroll
        for (int r = 0; r < 4; ++r)
          pA[(mt*16 + quad*4 + r)*136 + wave*32 + nt*16 + fr] = (bf16)oacc[mt][nt][r];
  }
  __syncthreads();

  {
    const int b = bh >> 3, h = bh & 7;
    #pragma unroll
    for (int r = 0; r < 4; ++r) {
      const int f = r*2048 + tid*8;
      const int i = f >> 7, e0 = f & 127;
      bf16x8 w = *(const bf16x8*)&pA[i*136 + e0];
      *(bf16x8*)&aout[((size_t)(b*4096 + u*64 + i))*1024 + h*128 + e0] = w;
    }
  }
}

// ---------------------------------------------------------------------------
extern "C" void kernel_launch(void* const* d_in, const int* in_sizes, int n_in,
                              void* d_out, int out_size, void* d_ws, size_t ws_size,
                              hipStream_t stream)
{
  (void)in_sizes; (void)n_in; (void)out_size; (void)ws_size;
  const void* x      = d_in[0];   // (4,4096,1024)
  const void* w_qkv  = d_in[1];   // (3072,1024)
  const void* sort_w = d_in[2];   // (1,8,128,64)
  const void* w_out  = d_in[3];   // (1024,1024)
  const void* b_out  = d_in[4];   // (1024,)
  const void* noise  = d_in[5];   // (32,64,64)

  char* ws = (char*)d_ws;
  const size_t TEN = (size_t)32*64*64*128;     // 16,777,216 elements
  const size_t HEN = TEN / 2;                  // per-half kre/vre elements
  bf16* q_ws  = (bf16*)ws;
  bf16* k_ws  = q_ws + TEN;
  bf16* vT_ws = k_ws + TEN;                    // [bh][u][e][i]
  bf16* xa_ws = vT_ws + TEN;                   // x-as-bf16, later attn out (b,t,d)

  // bkr/R live in the xa tail (b=3 rows of aout, overwritten only by attn h2)
  float* bkr_g = (float*)((char*)xa_ws + (size_t)30*1024*1024);   // 1 MiB
  float* R_buf = (float*)((char*)xa_ws + (size_t)31*1024*1024);   // 512 KiB
  // d_out scratch
  bf16* wqkv_bf = (bf16*)((char*)d_out + (1536<<10));  // 6 MiB, dead after gemm1
  bf16* kre = (bf16*)d_out;                            // 16 MiB per half
  bf16* vre = kre + HEN;                               // 16 MiB per half
  bf16* wout_bf = k_ws;                                // reused after attn

  convert_pair<<<9728, 256, 0, stream>>>(x, xa_ws, w_qkv, wqkv_bf, x);

  gemm256<0><<<dim3(12,64), 512, 0, stream>>>(xa_ws, wqkv_bf, nullptr,
                                              q_ws, k_ws, vT_ws, x, 16384, 3072, 1024);

  bksum<<<dim3(8,32), 128, 0, stream>>>(k_ws, bkr_g);
  sinkhorn_R<<<32, 256, 0, stream>>>(bkr_g, sort_w, noise, R_buf, x);

  // half 1: bh 0..15 (writes aout b=0,1 -> xa[0,16Mi), R stays intact)
  permute_kv<<<dim3(32,16,2), 256, 0, stream>>>(R_buf, k_ws, vT_ws, kre, vre, 0);
  attn_mfma<<<dim3(64,16), 256, 0, stream>>>(q_ws, k_ws, vT_ws, kre, vre, xa_ws, 0);
  // half 2: bh 16..31 (attn clobbers xa tail incl. bkr/R after R is consumed)
  permute_kv<<<dim3(32,16,2), 256, 0, stream>>>(R_buf, k_ws, vT_ws, kre, vre, 16);
  attn_mfma<<<dim3(64,16), 256, 0, stream>>>(q_ws, k_ws, vT_ws, kre, vre, xa_ws, 16);

  convert_to_bf16<<<512, 256, 0, stream>>>(w_out, wout_bf, x);
  gemm256<1><<<dim3(4,64), 512, 0, stream>>>(xa_ws, wout_bf, b_out,
                                             d_out, nullptr, nullptr, x, 16384, 1024, 1024);
}

// Round 7
// 424.416 us; speedup vs baseline: 1.3842x; 1.0146x over previous
//
#include <hip/hip_runtime.h>
#include <hip/hip_bf16.h>
#include <cstdint>
#include <cstddef>
#include <math.h>
#include <type_traits>

typedef __bf16 bf16;
typedef __bf16 bf16x4 __attribute__((ext_vector_type(4)));
typedef __bf16 bf16x8 __attribute__((ext_vector_type(8)));
typedef float  f32x4  __attribute__((ext_vector_type(4)));
typedef unsigned u32x2 __attribute__((ext_vector_type(2)));

// Shapes: B=4, T=4096, D=1024, H=8, DH=128, BUCKETS=64, BSZ=64, BH=32
// ws (128 MiB): q[bh][u][i][e] | k[bh][u][i][e] | vT[bh][u][e][i] | xa
// xa region (32 MiB): x-as-bf16 (dead after gemm1) -> bkr@+30Mi, R@+31Mi
//   (dead after 2nd permute_kv) -> aout (attn output, b-major)
// d_out scratch: wqkv_bf @+1.5Mi (dead after gemm1) -> kre 16Mi | vre 16Mi
//   per bh-half (dead before gemm2 writes d_out).
// Schedule: gemm1 -> bksum -> sinkhorn -> [permute+attn] x 2 halves -> gemm2.

__device__ inline bool input_is_fp32(const void* x) {
  const unsigned short* u = (const unsigned short*)x;
  const int lane = threadIdx.x & 63;
  const int e = (u[lane] >> 7) & 0xFF;
  return __ballot(e >= 137) != 0ULL;
}

__device__ inline float ldx(const void* p, size_t i, bool f32) {
  return f32 ? ((const float*)p)[i] : (float)((const bf16*)p)[i];
}

template<typename T>
__device__ inline bf16x8 ld8bf(const void* p, size_t i) {
  if constexpr (std::is_same<T, float>::value) {
    const f32x4* q = (const f32x4*)((const float*)p + i);
    const f32x4 a = q[0], b = q[1];
    bf16x8 r;
    r[0]=(bf16)a[0]; r[1]=(bf16)a[1]; r[2]=(bf16)a[2]; r[3]=(bf16)a[3];
    r[4]=(bf16)b[0]; r[5]=(bf16)b[1]; r[6]=(bf16)b[2]; r[7]=(bf16)b[3];
    return r;
  } else {
    return *(const bf16x8*)((const bf16*)p + i);
  }
}

// async global->LDS, 16 B per lane; LDS dest = wave-uniform base + lane*16
__device__ __forceinline__ void gload16(const void* g, void* l) {
  __builtin_amdgcn_global_load_lds(
      (__attribute__((address_space(1))) void*)g,
      (__attribute__((address_space(3))) void*)l, 16, 0, 0);
}

// ---------------------------------------------------------------------------
// dtype-flexible fp32/bf16 -> bf16 copy. One thread = 8 elements.
// ---------------------------------------------------------------------------
__global__ __launch_bounds__(256)
void convert_to_bf16(const void* __restrict__ src, bf16* __restrict__ dst,
                     const void* __restrict__ xdet) {
  const bool f32 = input_is_fp32(xdet);
  const size_t i = ((size_t)blockIdx.x * 256 + threadIdx.x) * 8;
  if (f32) *(bf16x8*)&dst[i] = ld8bf<float>(src, i);
  else     *(bf16x8*)&dst[i] = ld8bf<bf16 >(src, i);
}

// merged x + wqkv convert (one launch): blocks [0,8192) -> s1, [8192,9728) -> s2
__global__ __launch_bounds__(256)
void convert_pair(const void* __restrict__ s1, bf16* __restrict__ d1,
                  const void* __restrict__ s2, bf16* __restrict__ d2,
                  const void* __restrict__ xdet) {
  const bool f32 = input_is_fp32(xdet);
  const size_t b = blockIdx.x;
  if (b < 8192) {
    const size_t i = (b*256 + threadIdx.x) * 8;
    if (f32) *(bf16x8*)&d1[i] = ld8bf<float>(s1, i);
    else     *(bf16x8*)&d1[i] = ld8bf<bf16 >(s1, i);
  } else {
    const size_t i = ((b - 8192)*256 + threadIdx.x) * 8;
    if (f32) *(bf16x8*)&d2[i] = ld8bf<float>(s2, i);
    else     *(bf16x8*)&d2[i] = ld8bf<bf16 >(s2, i);
  }
}

// ---------------------------------------------------------------------------
// 256x256 8-phase GEMM: C[m][n] = sum_k A[m][k]*B[n][k], bf16 K-contiguous.
// BK=64 as two k-halves; LDS [buf][A/B][kh][256x32] = 128 KiB, 8 waves (2Mx4N).
// RACE-FREE half-tile read-ahead: single vmcnt(4) at ph4 (12 loads in flight,
// oldest 8 = ENTIRE tile t+1) + tile-entry barrier => whole current tile
// globally proven before any read. ph1 issues all 12 kh0 ds_reads ->
// lgkmcnt(4) -> MFMA(A0,B0); ph2 lgkmcnt(0) (A1 drained under ph1 MFMA) ->
// MFMA(A1,B0); ph3/ph4 same for kh1. WAR: each stage overwrites a buffer
// whose reads were proven retired (lgkmcnt(0)+barrier) >=2 barriers earlier.
// XCD-bijective blockIdx swizzle (nwg%8==0 both call sites).
// Swizzle: 16-B granule g ^= (row>>1)&3 on BOTH stage-src and ds_read (0 conf).
// EPI=0: scatter into q/k ([u][i][e]) and vT ([u][e][i]). EPI=1: bias+dtype.
// ---------------------------------------------------------------------------
template<int EPI>
__global__ __launch_bounds__(512, 2)
void gemm256(const bf16* __restrict__ A, const bf16* __restrict__ Bm,
             const void* __restrict__ bias,
             void* __restrict__ C0, bf16* __restrict__ C1, bf16* __restrict__ C2,
             const void* __restrict__ xdet, int M, int N, int K)
{
  __shared__ __align__(16) bf16 lds[2][2][2][8192];   // [buf][A/B][kh][256*32]
  const int tid = threadIdx.x, wave = tid >> 6, lane = tid & 63;
  const int fr = lane & 15, quad = lane >> 4;
  // XCD swizzle: orig bid b -> XCD b%8; logical tile = (b%8)*cpx + b/8
  const int nwg = gridDim.x * gridDim.y;
  const int cpx = nwg >> 3;
  const int bid = blockIdx.y * gridDim.x + blockIdx.x;
  const int swz = (bid & 7) * cpx + (bid >> 3);
  const int m0 = (swz / gridDim.x) * 256, n0 = (swz % gridDim.x) * 256;
  const int wm = wave >> 2, wn = wave & 3;            // 2 x 4 wave grid
  const int gsz  = (quad ^ ((fr >> 1) & 3)) * 16;     // swizzled read granule (bytes)
  const int srow = wave * 32 + (lane >> 2);           // staging row (first of 2)
  const int sg   = ((lane & 3) ^ ((lane >> 3) & 3)) * 8; // swizzled src col (elems)
  const int NT = K >> 6;
  char* ldsb = (char*)&lds[0][0][0][0];

  auto stageA = [&](int buf, int kh, int t) {
    const bf16* s = A + (size_t)(m0 + srow) * K + t*64 + kh*32 + sg;
    char* d = ldsb + buf*65536 + kh*16384 + wave*2048;
    gload16(s, d);
    gload16(s + (size_t)16 * K, d + 1024);
  };
  auto stageB = [&](int buf, int kh, int t) {
    const bf16* s = Bm + (size_t)(n0 + srow) * K + t*64 + kh*32 + sg;
    char* d = ldsb + buf*65536 + 32768 + kh*16384 + wave*2048;
    gload16(s, d);
    gload16(s + (size_t)16 * K, d + 1024);
  };
  auto lda = [&](int c, int kh, int fi) {
    return *(const bf16x8*)(ldsb + c*65536 + kh*16384 + (wm*128 + fi*16 + fr)*64 + gsz);
  };
  auto ldb = [&](int c, int kh, int fi) {
    return *(const bf16x8*)(ldsb + c*65536 + 32768 + kh*16384 + (wn*64 + fi*16 + fr)*64 + gsz);
  };

  f32x4 acc[8][4];
  #pragma unroll
  for (int a = 0; a < 8; ++a)
    #pragma unroll
    for (int b = 0; b < 4; ++b) { f32x4 z = {0.f,0.f,0.f,0.f}; acc[a][b] = z; }

  bf16x8 A0[4], A1[4], B0[4], B1[4];

  // prologue: tile0 kh0+kh1, tile1 kh0 (12 loads); vmcnt(4) proves tile 0
  // fully resident (oldest 8), leaves tile1-k0 (4) in flight.
  stageA(0, 0, 0); stageB(0, 0, 0);
  stageA(0, 1, 0); stageB(0, 1, 0);
  stageA(1, 0, 1); stageB(1, 0, 1);
  asm volatile("s_waitcnt vmcnt(4)" ::: "memory");
  __builtin_amdgcn_s_barrier();

  #pragma unroll 1
  for (int t = 0; t < NT; ++t) {
    const int c = t & 1;
    const bool d12 = (t + 1 < NT), d34 = (t + 2 < NT);

    // ---- ph1: issue all 12 kh0 reads; stage A(t+1)k1; MFMA(A0,B0)
    #pragma unroll
    for (int n = 0; n < 4; ++n) B0[n] = ldb(c, 0, n);
    #pragma unroll
    for (int m = 0; m < 4; ++m) A0[m] = lda(c, 0, m);
    #pragma unroll
    for (int m = 0; m < 4; ++m) A1[m] = lda(c, 0, 4 + m);
    if (d12) stageA(c ^ 1, 1, t + 1);
    __builtin_amdgcn_s_barrier();
    asm volatile("s_waitcnt lgkmcnt(4)" ::: "memory");
    __builtin_amdgcn_sched_barrier(0);
    __builtin_amdgcn_s_setprio(1);
    #pragma unroll
    for (int m = 0; m < 4; ++m)
      #pragma unroll
      for (int n = 0; n < 4; ++n)
        acc[m][n] = __builtin_amdgcn_mfma_f32_16x16x32_bf16(A0[m], B0[n], acc[m][n], 0, 0, 0);
    __builtin_amdgcn_s_setprio(0);
    __builtin_amdgcn_s_barrier();

    // ---- ph2: stage B(t+1)k1; MFMA(A1,B0) (A1 drained under ph1 MFMA)
    if (d12) stageB(c ^ 1, 1, t + 1);
    __builtin_amdgcn_s_barrier();
    asm volatile("s_waitcnt lgkmcnt(0)" ::: "memory");
    __builtin_amdgcn_sched_barrier(0);
    __builtin_amdgcn_s_setprio(1);
    #pragma unroll
    for (int m = 0; m < 4; ++m)
      #pragma unroll
      for (int n = 0; n < 4; ++n)
        acc[4 + m][n] = __builtin_amdgcn_mfma_f32_16x16x32_bf16(A1[m], B0[n], acc[4 + m][n], 0, 0, 0);
    __builtin_amdgcn_s_setprio(0);
    __builtin_amdgcn_s_barrier();

    // ---- ph3: issue all 12 kh1 reads; stage A(t+2)k0; MFMA(A0,B1)
    #pragma unroll
    for (int n = 0; n < 4; ++n) B1[n] = ldb(c, 1, n);
    #pragma unroll
    for (int m = 0; m < 4; ++m) A0[m] = lda(c, 1, m);
    #pragma unroll
    for (int m = 0; m < 4; ++m) A1[m] = lda(c, 1, 4 + m);
    if (d34) stageA(c, 0, t + 2);
    __builtin_amdgcn_s_barrier();
    asm volatile("s_waitcnt lgkmcnt(4)" ::: "memory");
    __builtin_amdgcn_sched_barrier(0);
    __builtin_amdgcn_s_setprio(1);
    #pragma unroll
    for (int m = 0; m < 4; ++m)
      #pragma unroll
      for (int n = 0; n < 4; ++n)
        acc[m][n] = __builtin_amdgcn_mfma_f32_16x16x32_bf16(A0[m], B1[n], acc[m][n], 0, 0, 0);
    __builtin_amdgcn_s_setprio(0);
    __builtin_amdgcn_s_barrier();

    // ---- ph4: stage B(t+2)k0; MFMA(A1,B1); vmcnt proves tile t+1 resident
    if (d34) stageB(c, 0, t + 2);
    __builtin_amdgcn_s_barrier();
    asm volatile("s_waitcnt lgkmcnt(0)" ::: "memory");
    __builtin_amdgcn_sched_barrier(0);
    __builtin_amdgcn_s_setprio(1);
    #pragma unroll
    for (int m = 0; m < 4; ++m)
      #pragma unroll
      for (int n = 0; n < 4; ++n)
        acc[4 + m][n] = __builtin_amdgcn_mfma_f32_16x16x32_bf16(A1[m], B1[n], acc[4 + m][n], 0, 0, 0);
    __builtin_amdgcn_s_setprio(0);
    if (t < NT - 2)       { asm volatile("s_waitcnt vmcnt(4)" ::: "memory"); }
    else if (t == NT - 2) { asm volatile("s_waitcnt vmcnt(0)" ::: "memory"); }
    __builtin_amdgcn_s_barrier();
  }

  // C/D layout: col = lane&15 (fr), row = quad*4 + reg
  if constexpr (EPI == 0) {
    const int sel = n0 >> 10;               // block-uniform (n0 mult of 256)
    const int cb  = (n0 & 1023) + wn * 64;
    #pragma unroll
    for (int im = 0; im < 8; ++im) {
      const int mrow = m0 + wm*128 + im*16 + quad*4;
      const int b = mrow >> 12, tt = mrow & 4095;
      const int u = tt >> 6, i = tt & 63;   // i..i+3 stay in-bucket
      #pragma unroll
      for (int nn = 0; nn < 4; ++nn) {
        const int cc = cb + nn*16 + fr;
        const int h = cc >> 7, e = cc & 127;
        const size_t bhu = (size_t)((b*8 + h)*64 + u);
        if (sel == 2) {                     // vT [u][e][i]: one 8-B store
          bf16x4 w;
          #pragma unroll
          for (int r = 0; r < 4; ++r) w[r] = (bf16)acc[im][nn][r];
          *(bf16x4*)&C2[(bhu*128 + e)*64 + i] = w;
        } else {                            // q/k [u][i][e]
          bf16* dst = (sel == 0) ? (bf16*)C0 : C1;
          #pragma unroll
          for (int r = 0; r < 4; ++r)
            dst[(bhu*64 + i + r)*128 + e] = (bf16)acc[im][nn][r];
        }
      }
    }
  } else {
    const bool f32o = input_is_fp32(xdet);
    #pragma unroll
    for (int im = 0; im < 8; ++im) {
      #pragma unroll
      for (int nn = 0; nn < 4; ++nn) {
        #pragma unroll
        for (int r = 0; r < 4; ++r) {
          const int m = m0 + wm*128 + im*16 + quad*4 + r;
          const int n = n0 + wn*64 + nn*16 + fr;
          const float val = acc[im][nn][r] + ldx(bias, n, f32o);
          if (f32o) ((float*)C0)[(size_t)m*N + n] = val;
          else      ((bf16*)C0)[(size_t)m*N + n] = (bf16)val;
        }
      }
    }
  }
}

// ---------------------------------------------------------------------------
// bksum: bkr[bh][u][e] = sum_i k[bh][u][i][e]. grid (8,32), 128 threads.
// ---------------------------------------------------------------------------
__global__ __launch_bounds__(128)
void bksum(const bf16* __restrict__ k_ws, float* __restrict__ bkr_g)
{
  const int ug = blockIdx.x, bh = blockIdx.y, t = threadIdx.x;
  const int ul = t >> 4, e0 = (t & 15) * 8;
  const int u = ug * 8 + ul;
  const bf16* p = k_ws + ((size_t)bh*64 + u)*8192 + e0;
  float acc[8];
  #pragma unroll
  for (int j = 0; j < 8; ++j) acc[j] = 0.f;
  for (int i = 0; i < 64; ++i) {
    bf16x8 kv = *(const bf16x8*)&p[i*128];
    #pragma unroll
    for (int j = 0; j < 8; ++j) acc[j] += (float)kv[j];
  }
  float* dst = bkr_g + (size_t)bh*8192 + u*128 + e0;
  #pragma unroll
  for (int j = 0; j < 8; ++j) dst[j] = acc[j];
}

// ---------------------------------------------------------------------------
// Sinkhorn R per bh (32 blocks, 256 threads). Gumbel inner expr in fp64.
// LSE phases parallelized: 4 threads/row (or col) + shfl_xor(1,2) reduce.
// ---------------------------------------------------------------------------
__global__ __launch_bounds__(256)
void sinkhorn_R(const float* __restrict__ bkr_g, const void* __restrict__ sort_w,
                const void* __restrict__ noise, float* __restrict__ R_buf,
                const void* __restrict__ xdet)
{
  const bool f32 = input_is_fp32(xdet);
  const int bh = blockIdx.x, h = bh & 7, tid = threadIdx.x;
  __shared__ float bkr[64*128];
  __shared__ float ew[128*64];
  __shared__ float R[64*65];

  for (int f = tid; f < 64*128; f += 256) bkr[f] = bkr_g[(size_t)bh*8192 + f];
  for (int f = tid; f < 128*64; f += 256) ew[f] = ldx(sort_w, (size_t)h*8192 + f, f32);
  __syncthreads();

  for (int f = tid; f < 64*64; f += 256) {
    const int u = f >> 6, v = f & 63;
    float s = 0.f;
    for (int e = 0; e < 128; ++e) s += bkr[u*128 + e] * ew[e*64 + v];
    s = fmaxf(s, 0.f);
    const float r  = logf(s + 1e-6f);
    const double nz = (double)ldx(noise, ((size_t)bh*64 + u)*64 + v, f32);
    const double t1 = log(nz + 1e-4);
    const double t2 = fmax(-t1 + 1e-4, 1e-30);
    const float g = (float)(-log(t2));
    R[u*65 + v] = (r + g) * (1.f / 0.75f);
  }
  __syncthreads();

  const int rc = tid >> 2, c4 = tid & 3;   // 4 lanes per row/col (same quad)
  for (int it = 0; it < 5; ++it) {
    {  // row LSE
      float mx = -1e30f;
      for (int v = c4; v < 64; v += 4) mx = fmaxf(mx, R[rc*65 + v]);
      mx = fmaxf(mx, __shfl_xor(mx, 1));
      mx = fmaxf(mx, __shfl_xor(mx, 2));
      float s = 0.f;
      for (int v = c4; v < 64; v += 4) s += expf(R[rc*65 + v] - mx);
      s += __shfl_xor(s, 1);
      s += __shfl_xor(s, 2);
      const float l = mx + logf(s);
      for (int v = c4; v < 64; v += 4) R[rc*65 + v] -= l;
    }
    __syncthreads();
    {  // col LSE
      float mx = -1e30f;
      for (int u = c4; u < 64; u += 4) mx = fmaxf(mx, R[u*65 + rc]);
      mx = fmaxf(mx, __shfl_xor(mx, 1));
      mx = fmaxf(mx, __shfl_xor(mx, 2));
      float s = 0.f;
      for (int u = c4; u < 64; u += 4) s += expf(R[u*65 + rc] - mx);
      s += __shfl_xor(s, 1);
      s += __shfl_xor(s, 2);
      const float l = mx + logf(s);
      for (int u = c4; u < 64; u += 4) R[u*65 + rc] -= l;
    }
    __syncthreads();
  }

  for (int f = tid; f < 64*64; f += 256) {
    const int u = f >> 6, v = f & 63;
    R_buf[(size_t)bh*4096 + f] = (u > v) ? expf(R[u*65 + v]) : 0.f;
  }
}

// ---------------------------------------------------------------------------
// permute_kv: Out[bhl][u][f] = sum_v R[bh][u][v] * X[bh][v][f]  (f = 8192)
// One block = (256-f chunk, bh-local, tensor z). R as bf16 hi+lo (K=128) for
// ~fp32 weight precision. X staged into 16-f subtiles [64 v][16 f] row-major.
// B-frags via ds_read_b64_tr_b16 (lane addr = win + 8*(lane&15) bytes).
// ---------------------------------------------------------------------------
__global__ __launch_bounds__(256)
void permute_kv(const float* __restrict__ R_buf,
                const bf16* __restrict__ Xk, const bf16* __restrict__ Xv,
                bf16* __restrict__ Ok, bf16* __restrict__ Ov, int bh0)
{
  const int tid = threadIdx.x;
  const int bhl = blockIdx.y, bh = bh0 + bhl;
  const int f0  = blockIdx.x * 256;
  const bf16* X = blockIdx.z ? Xv : Xk;
  bf16*       O = blockIdx.z ? Ov : Ok;

  __shared__ __align__(16) bf16 A_lds[64*136];    // R hi|lo, padded stride 136
  __shared__ __align__(16) bf16 X_lds[16*1048];   // 16 fgrps x [64 v][16 f]

  // stage X tile [64 v][256 f]: X_lds[fgrp][v][j] = X[v][f0 + fgrp*16 + j]
  {
    const bf16* Xg = X + (size_t)bh*524288 + f0;
    const int vb = tid >> 5, c = tid & 31;        // c: 8-f chunk
    const int dst = (c >> 1)*1048 + (c & 1)*8;
    #pragma unroll
    for (int p = 0; p < 8; ++p) {
      const int v = vb + p*8;
      *(bf16x8*)&X_lds[dst + v*16] = *(const bf16x8*)&Xg[(size_t)v*8192 + c*8];
    }
  }
  // stage R split: A[u][v]=hi(R), A[u][64+v]=lo(R)
  {
    const float* Rg = R_buf + (size_t)bh*4096;
    #pragma unroll
    for (int p = 0; p < 16; ++p) {
      const int idx = tid + p*256;
      const int uu = idx >> 6, vv = idx & 63;
      const float r = Rg[idx];
      const bf16 hi = (bf16)r;
      const float lo = r - (float)hi;
      A_lds[uu*136 + vv]      = hi;
      A_lds[uu*136 + 64 + vv] = (bf16)lo;
    }
  }
  __syncthreads();

  const int lane = tid & 63, wave = tid >> 6;
  const int fr = lane & 15, quad = lane >> 4;

  bf16x8 af[4][4];
  #pragma unroll
  for (int mt = 0; mt < 4; ++mt)
    #pragma unroll
    for (int ks = 0; ks < 4; ++ks)
      af[mt][ks] = *(const bf16x8*)&A_lds[(mt*16 + fr)*136 + ks*32 + quad*8];

  f32x4 acc[4][4];
  #pragma unroll
  for (int a = 0; a < 4; ++a)
    #pragma unroll
    for (int b = 0; b < 4; ++b) { f32x4 z = {0.f,0.f,0.f,0.f}; acc[a][b] = z; }

  #pragma unroll
  for (int nt = 0; nt < 4; ++nt) {
    const int g = wave*4 + nt;
    // per-lane addr (BYTES) = 2096*g + 256*quad + 8*fr  ->  elems: +4*fr
    const unsigned addr = (unsigned)(size_t)
        (__attribute__((address_space(3))) bf16*)&X_lds[g*1048 + quad*128 + fr*4];
    u32x2 p0, p1, p2, p3;
    asm volatile(
      "ds_read_b64_tr_b16 %0, %4\n"
      "ds_read_b64_tr_b16 %1, %4 offset:128\n"
      "ds_read_b64_tr_b16 %2, %4 offset:1024\n"
      "ds_read_b64_tr_b16 %3, %4 offset:1152\n"
      : "=&v"(p0), "=&v"(p1), "=&v"(p2), "=&v"(p3)
      : "v"(addr));
    asm volatile("s_waitcnt lgkmcnt(0)" ::: "memory");
    __builtin_amdgcn_sched_barrier(0);
    union { u32x2 u[2]; bf16x8 v; } c0, c1;
    c0.u[0] = p0; c0.u[1] = p1;               // v = quad*8 + 0..7  (v-slice 0..31)
    c1.u[0] = p2; c1.u[1] = p3;               // v-slice 32..63
    const bf16x8 b0 = c0.v, b1 = c1.v;
    #pragma unroll
    for (int mt = 0; mt < 4; ++mt) {
      acc[mt][nt] = __builtin_amdgcn_mfma_f32_16x16x32_bf16(af[mt][0], b0, acc[mt][nt], 0, 0, 0);
      acc[mt][nt] = __builtin_amdgcn_mfma_f32_16x16x32_bf16(af[mt][1], b1, acc[mt][nt], 0, 0, 0);
      acc[mt][nt] = __builtin_amdgcn_mfma_f32_16x16x32_bf16(af[mt][2], b0, acc[mt][nt], 0, 0, 0);
      acc[mt][nt] = __builtin_amdgcn_mfma_f32_16x16x32_bf16(af[mt][3], b1, acc[mt][nt], 0, 0, 0);
    }
  }

  bf16* Og = O + (size_t)bhl*524288 + f0;
  #pragma unroll
  for (int mt = 0; mt < 4; ++mt)
    #pragma unroll
    for (int nt = 0; nt < 4; ++nt)
      #pragma unroll
      for (int r = 0; r < 4; ++r)
        Og[(size_t)(mt*16 + quad*4 + r)*8192 + wave*64 + nt*16 + fr] = (bf16)acc[mt][nt][r];
}

// ---------------------------------------------------------------------------
// MFMA bucketed attention, streaming: kre/vre precomputed in global scratch.
// One block per (bh,u), 256 threads; every K/V byte read exactly once.
// T14: cold vT PV-fragments issued BEFORE dots so HBM latency hides under
// QK^T + softmax (vre is L2/L3-warm from permute; not prefetched).
// ---------------------------------------------------------------------------
__global__ __launch_bounds__(256)
void attn_mfma(const bf16* __restrict__ q_ws, const bf16* __restrict__ k_ws,
               const bf16* __restrict__ vT_ws,
               const bf16* __restrict__ kre_g, const bf16* __restrict__ vre_g,
               bf16* __restrict__ aout, int bh0)
{
  const int u = blockIdx.x, bhl = blockIdx.y, bh = bh0 + bhl;
  const int tid = threadIdx.x;
  const int lane = tid & 63, wave = tid >> 6;
  const int fr = lane & 15, quad = lane >> 4;

  __shared__ __align__(16) unsigned char smem[34048];
  float* sc = (float*)smem;                 // 64 x (stride 132)
  bf16*  pA = (bf16*)smem;                  // alias, stride 136

  const size_t tileq = ((size_t)bh *64 + u) * 8192;   // q/k/vT/aout (global bh)
  const size_t tilel = ((size_t)bhl*64 + u) * 8192;   // kre/vre (half-local bh)

  // T14 prefetch: vT frags for PV (ks = 2,3), 16 VGPR held across dots+softmax
  bf16x8 pvT[2][2];
  #pragma unroll
  for (int nt = 0; nt < 2; ++nt) {
    const int e = wave*32 + nt*16 + fr;
    #pragma unroll
    for (int k2 = 0; k2 < 2; ++k2)
      pvT[nt][k2] = *(const bf16x8*)&vT_ws[tileq + (size_t)e*64 + k2*32 + quad*8];
  }

  {
    f32x4 dacc[4][2];
    #pragma unroll
    for (int mt = 0; mt < 4; ++mt)
      #pragma unroll
      for (int nt = 0; nt < 2; ++nt) { f32x4 z = {0.f,0.f,0.f,0.f}; dacc[mt][nt] = z; }
    #pragma unroll
    for (int ks = 0; ks < 4; ++ks) {
      bf16x8 afr[4];
      #pragma unroll
      for (int mt = 0; mt < 4; ++mt)
        afr[mt] = *(const bf16x8*)&q_ws[tileq + (size_t)(mt*16 + fr)*128 + ks*32 + quad*8];
      #pragma unroll
      for (int nt = 0; nt < 2; ++nt) {
        const int j = wave*32 + nt*16 + fr;
        bf16x8 bfr;
        if (wave < 2) bfr = *(const bf16x8*)&kre_g[tilel + (size_t)j*128 + ks*32 + quad*8];
        else          bfr = *(const bf16x8*)&k_ws[tileq + (size_t)(j - 64)*128 + ks*32 + quad*8];
        #pragma unroll
        for (int mt = 0; mt < 4; ++mt)
          dacc[mt][nt] = __builtin_amdgcn_mfma_f32_16x16x32_bf16(afr[mt], bfr, dacc[mt][nt], 0, 0, 0);
      }
    }
    #pragma unroll
    for (int mt = 0; mt < 4; ++mt)
      #pragma unroll
      for (int nt = 0; nt < 2; ++nt)
        #pragma unroll
        for (int r = 0; r < 4; ++r)
          sc[(mt*16 + quad*4 + r)*132 + wave*32 + nt*16 + fr] = dacc[mt][nt][r] * 0.03125f;
  }
  __syncthreads();

  {
    const int i = tid >> 2, jc = tid & 3;
    float pv[32];
    float mx = -1e30f;
    #pragma unroll
    for (int t = 0; t < 32; ++t) { pv[t] = sc[i*132 + jc + t*4]; mx = fmaxf(mx, pv[t]); }
    mx = fmaxf(mx, __shfl_xor(mx, 1));
    mx = fmaxf(mx, __shfl_xor(mx, 2));
    float s = 0.f;
    #pragma unroll
    for (int t = 0; t < 32; ++t) { pv[t] = expf(pv[t] - mx); s += pv[t]; }
    s += __shfl_xor(s, 1);
    s += __shfl_xor(s, 2);
    const float inv = 1.f / s;
    __syncthreads();
    #pragma unroll
    for (int t = 0; t < 32; ++t) pA[i*136 + jc + t*4] = (bf16)(pv[t] * inv);
  }
  __syncthreads();

  {
    f32x4 oacc[4][2];
    #pragma unroll
    for (int mt = 0; mt < 4; ++mt)
      #pragma unroll
      for (int nt = 0; nt < 2; ++nt) { f32x4 z = {0.f,0.f,0.f,0.f}; oacc[mt][nt] = z; }
    #pragma unroll
    for (int ks = 0; ks < 4; ++ks) {
      bf16x8 afr[4];
      #pragma unroll
      for (int mt = 0; mt < 4; ++mt)
        afr[mt] = *(const bf16x8*)&pA[(mt*16 + fr)*136 + ks*32 + quad*8];
      #pragma unroll
      for (int nt = 0; nt < 2; ++nt) {
        bf16x8 bfr;
        if (ks < 2) {
          const int e = wave*32 + nt*16 + fr;
          bfr = *(const bf16x8*)&vre_g[tilel + (size_t)e*64 + ks*32 + quad*8];
        } else {
          bfr = pvT[nt][ks - 2];
        }
        #pragma unroll
        for (int mt = 0; mt < 4; ++mt)
          oacc[mt][nt] = __builtin_amdgcn_mfma_f32_16x16x32_bf16(afr[mt], bfr, oacc[mt][nt], 0, 0, 0);
      }
    }
    __syncthreads();
    #pragma unroll
    for (int mt = 0; mt < 4; ++mt)
      #pragma unroll
      for (int nt = 0; nt < 2; ++nt)
        #pragma unroll
        for (int r = 0; r < 4; ++r)
          pA[(mt*16 + quad*4 + r)*136 + wave*32 + nt*16 + fr] = (bf16)oacc[mt][nt][r];
  }
  __syncthreads();

  {
    const int b = bh >> 3, h = bh & 7;
    #pragma unroll
    for (int r = 0; r < 4; ++r) {
      const int f = r*2048 + tid*8;
      const int i = f >> 7, e0 = f & 127;
      bf16x8 w = *(const bf16x8*)&pA[i*136 + e0];
      *(bf16x8*)&aout[((size_t)(b*4096 + u*64 + i))*1024 + h*128 + e0] = w;
    }
  }
}

// ---------------------------------------------------------------------------
extern "C" void kernel_launch(void* const* d_in, const int* in_sizes, int n_in,
                              void* d_out, int out_size, void* d_ws, size_t ws_size,
                              hipStream_t stream)
{
  (void)in_sizes; (void)n_in; (void)out_size; (void)ws_size;
  const void* x      = d_in[0];   // (4,4096,1024)
  const void* w_qkv  = d_in[1];   // (3072,1024)
  const void* sort_w = d_in[2];   // (1,8,128,64)
  const void* w_out  = d_in[3];   // (1024,1024)
  const void* b_out  = d_in[4];   // (1024,)
  const void* noise  = d_in[5];   // (32,64,64)

  char* ws = (char*)d_ws;
  const size_t TEN = (size_t)32*64*64*128;     // 16,777,216 elements
  const size_t HEN = TEN / 2;                  // per-half kre/vre elements
  bf16* q_ws  = (bf16*)ws;
  bf16* k_ws  = q_ws + TEN;
  bf16* vT_ws = k_ws + TEN;                    // [bh][u][e][i]
  bf16* xa_ws = vT_ws + TEN;                   // x-as-bf16, later attn out (b,t,d)

  // bkr/R live in the xa tail (b=3 rows of aout, overwritten only by attn h2)
  float* bkr_g = (float*)((char*)xa_ws + (size_t)30*1024*1024);   // 1 MiB
  float* R_buf = (float*)((char*)xa_ws + (size_t)31*1024*1024);   // 512 KiB
  // d_out scratch
  bf16* wqkv_bf = (bf16*)((char*)d_out + (1536<<10));  // 6 MiB, dead after gemm1
  bf16* kre = (bf16*)d_out;                            // 16 MiB per half
  bf16* vre = kre + HEN;                               // 16 MiB per half
  bf16* wout_bf = k_ws;                                // reused after attn

  convert_pair<<<9728, 256, 0, stream>>>(x, xa_ws, w_qkv, wqkv_bf, x);

  gemm256<0><<<dim3(12,64), 512, 0, stream>>>(xa_ws, wqkv_bf, nullptr,
                                              q_ws, k_ws, vT_ws, x, 16384, 3072, 1024);

  bksum<<<dim3(8,32), 128, 0, stream>>>(k_ws, bkr_g);
  sinkhorn_R<<<32, 256, 0, stream>>>(bkr_g, sort_w, noise, R_buf, x);

  // half 1: bh 0..15 (writes aout b=0,1 -> xa[0,16Mi), R stays intact)
  permute_kv<<<dim3(32,16,2), 256, 0, stream>>>(R_buf, k_ws, vT_ws, kre, vre, 0);
  attn_mfma<<<dim3(64,16), 256, 0, stream>>>(q_ws, k_ws, vT_ws, kre, vre, xa_ws, 0);
  // half 2: bh 16..31 (attn clobbers xa tail incl. bkr/R after R is consumed)
  permute_kv<<<dim3(32,16,2), 256, 0, stream>>>(R_buf, k_ws, vT_ws, kre, vre, 16);
  attn_mfma<<<dim3(64,16), 256, 0, stream>>>(q_ws, k_ws, vT_ws, kre, vre, xa_ws, 16);

  convert_to_bf16<<<512, 256, 0, stream>>>(w_out, wout_bf, x);
  gemm256<1><<<dim3(4,64), 512, 0, stream>>>(xa_ws, wout_bf, b_out,
                                             d_out, nullptr, nullptr, x, 16384, 1024, 1024);
}

// Round 8
// 422.929 us; speedup vs baseline: 1.3890x; 1.0035x over previous
//
#include <hip/hip_runtime.h>
#include <hip/hip_bf16.h>
#include <cstdint>
#include <cstddef>
#include <math.h>
#include <type_traits>

typedef __bf16 bf16;
typedef __bf16 bf16x4 __attribute__((ext_vector_type(4)));
typedef __bf16 bf16x8 __attribute__((ext_vector_type(8)));
typedef float  f32x4  __attribute__((ext_vector_type(4)));
typedef unsigned u32x2 __attribute__((ext_vector_type(2)));

// Shapes: B=4, T=4096, D=1024, H=8, DH=128, BUCKETS=64, BSZ=64, BH=32
// ws (128 MiB): q[bh][u][i][e] | k[bh][u][i][e] | vT[bh][u][e][i] | xa
// xa region (32 MiB): x-as-bf16 (dead after gemm1) -> bkr@+30Mi, R@+31Mi
//   (dead after 2nd permute_kv) -> aout (attn output, b-major)
// d_out scratch: wqkv_bf @+1.5Mi (dead after gemm1) -> kre 16Mi | vre 16Mi
//   per bh-half (dead before gemm2 writes d_out).
// Schedule: gemm1 -> bksum -> sinkhorn -> [permute+attn] x 2 halves -> gemm2.

__device__ inline bool input_is_fp32(const void* x) {
  const unsigned short* u = (const unsigned short*)x;
  const int lane = threadIdx.x & 63;
  const int e = (u[lane] >> 7) & 0xFF;
  return __ballot(e >= 137) != 0ULL;
}

__device__ inline float ldx(const void* p, size_t i, bool f32) {
  return f32 ? ((const float*)p)[i] : (float)((const bf16*)p)[i];
}

template<typename T>
__device__ inline bf16x8 ld8bf(const void* p, size_t i) {
  if constexpr (std::is_same<T, float>::value) {
    const f32x4* q = (const f32x4*)((const float*)p + i);
    const f32x4 a = q[0], b = q[1];
    bf16x8 r;
    r[0]=(bf16)a[0]; r[1]=(bf16)a[1]; r[2]=(bf16)a[2]; r[3]=(bf16)a[3];
    r[4]=(bf16)b[0]; r[5]=(bf16)b[1]; r[6]=(bf16)b[2]; r[7]=(bf16)b[3];
    return r;
  } else {
    return *(const bf16x8*)((const bf16*)p + i);
  }
}

// async global->LDS, 16 B per lane; LDS dest = wave-uniform base + lane*16
__device__ __forceinline__ void gload16(const void* g, void* l) {
  __builtin_amdgcn_global_load_lds(
      (__attribute__((address_space(1))) void*)g,
      (__attribute__((address_space(3))) void*)l, 16, 0, 0);
}

// ---------------------------------------------------------------------------
// dtype-flexible fp32/bf16 -> bf16 copy. One thread = 8 elements.
// ---------------------------------------------------------------------------
__global__ __launch_bounds__(256)
void convert_to_bf16(const void* __restrict__ src, bf16* __restrict__ dst,
                     const void* __restrict__ xdet) {
  const bool f32 = input_is_fp32(xdet);
  const size_t i = ((size_t)blockIdx.x * 256 + threadIdx.x) * 8;
  if (f32) *(bf16x8*)&dst[i] = ld8bf<float>(src, i);
  else     *(bf16x8*)&dst[i] = ld8bf<bf16 >(src, i);
}

// merged x + wqkv convert (one launch): blocks [0,8192) -> s1, [8192,9728) -> s2
__global__ __launch_bounds__(256)
void convert_pair(const void* __restrict__ s1, bf16* __restrict__ d1,
                  const void* __restrict__ s2, bf16* __restrict__ d2,
                  const void* __restrict__ xdet) {
  const bool f32 = input_is_fp32(xdet);
  const size_t b = blockIdx.x;
  if (b < 8192) {
    const size_t i = (b*256 + threadIdx.x) * 8;
    if (f32) *(bf16x8*)&d1[i] = ld8bf<float>(s1, i);
    else     *(bf16x8*)&d1[i] = ld8bf<bf16 >(s1, i);
  } else {
    const size_t i = ((b - 8192)*256 + threadIdx.x) * 8;
    if (f32) *(bf16x8*)&d2[i] = ld8bf<float>(s2, i);
    else     *(bf16x8*)&d2[i] = ld8bf<bf16 >(s2, i);
  }
}

// ---------------------------------------------------------------------------
// 256x128-tile GEMM, BK=32, 2 blocks/CU: C[m][n] = sum_k A[m][k]*B[n][k].
// LDS [2 buf][A 256x32 | B 128x32] = 48 KiB; 8 waves as 4M x 2N (64x64/wave,
// acc[4][4] = 64 VGPR; <=128 total under __launch_bounds__(512,4)) so TWO
// blocks co-reside per CU -- barrier/waitcnt stalls of one block are filled
// by the other (m114 wave-level overlap; rounds 6/7 showed intra-block
// reordering alone is neutral at 1 block/CU).
// Per tile: 8 ds_reads -> lgkmcnt(2) -> 8 MFMA -> lgkmcnt(0) -> 8 MFMA ->
// barrier (all reads of buf c retired) -> stage t+2 into buf c -> vmcnt(3)
// (3+3 outstanding; oldest 3 = tile t+1) -> barrier (t+1 globally resident).
// Tail: vmcnt(0) at t==NT-2. XCD-bijective swizzle (nwg%8==0 both sites).
// Bank swizzle: 16-B granule g ^= (row>>1)&3 on BOTH stage-src and ds_read.
// EPI=0: scatter into q/k ([u][i][e]) and vT ([u][e][i]). EPI=1: bias+dtype.
// ---------------------------------------------------------------------------
template<int EPI>
__global__ __launch_bounds__(512, 4)
void gemm256(const bf16* __restrict__ A, const bf16* __restrict__ Bm,
             const void* __restrict__ bias,
             void* __restrict__ C0, bf16* __restrict__ C1, bf16* __restrict__ C2,
             const void* __restrict__ xdet, int M, int N, int K)
{
  __shared__ __align__(16) bf16 lds[2][12288];        // [buf][A 16K | B 8K bytes]
  const int tid = threadIdx.x, wave = tid >> 6, lane = tid & 63;
  const int fr = lane & 15, quad = lane >> 4;
  // XCD swizzle: orig bid b -> XCD b%8; logical tile = (b%8)*cpx + b/8
  const int nwg = gridDim.x * gridDim.y;
  const int cpx = nwg >> 3;
  const int bid = blockIdx.y * gridDim.x + blockIdx.x;
  const int swz = (bid & 7) * cpx + (bid >> 3);
  const int m0 = (swz / gridDim.x) * 256, n0 = (swz % gridDim.x) * 128;
  const int wm = wave >> 1, wn = wave & 1;            // 4M x 2N wave grid
  const int gsz = (quad ^ ((fr >> 1) & 3)) * 16;      // swizzled read granule (bytes)
  const int sg  = ((lane & 3) ^ ((lane >> 3) & 3)) * 8; // swizzled src col (elems)
  const int NT = K >> 5;
  char* ldsb = (char*)&lds[0][0];

  auto stageA = [&](int buf, int t) {                 // 2 gloads: rows wave*32..+31
    const bf16* s = A + (size_t)(m0 + wave*32 + (lane >> 2)) * K + t*32 + sg;
    char* d = ldsb + buf*24576 + wave*2048;
    gload16(s, d);
    gload16(s + (size_t)16 * K, d + 1024);
  };
  auto stageB = [&](int buf, int t) {                 // 1 gload: rows wave*16..+15
    const bf16* s = Bm + (size_t)(n0 + wave*16 + (lane >> 2)) * K + t*32 + sg;
    char* d = ldsb + buf*24576 + 16384 + wave*1024;
    gload16(s, d);
  };
  auto lda = [&](int c, int fi) {
    return *(const bf16x8*)(ldsb + c*24576 + (wm*64 + fi*16 + fr)*64 + gsz);
  };
  auto ldb = [&](int c, int fi) {
    return *(const bf16x8*)(ldsb + c*24576 + 16384 + (wn*64 + fi*16 + fr)*64 + gsz);
  };

  f32x4 acc[4][4];
  #pragma unroll
  for (int a = 0; a < 4; ++a)
    #pragma unroll
    for (int b = 0; b < 4; ++b) { f32x4 z = {0.f,0.f,0.f,0.f}; acc[a][b] = z; }

  // prologue: tile0 -> buf0, tile1 -> buf1 (6 loads); vmcnt(3) proves tile0.
  stageA(0, 0); stageB(0, 0);
  stageA(1, 1); stageB(1, 1);
  asm volatile("s_waitcnt vmcnt(3)" ::: "memory");
  __builtin_amdgcn_s_barrier();

  #pragma unroll 1
  for (int t = 0; t < NT; ++t) {
    const int c = t & 1;
    bf16x8 Af[4], Bf[4];
    #pragma unroll
    for (int n = 0; n < 4; ++n) Bf[n] = ldb(c, n);
    #pragma unroll
    for (int m = 0; m < 4; ++m) Af[m] = lda(c, m);
    asm volatile("s_waitcnt lgkmcnt(2)" ::: "memory");   // B0-3,A0,A1 done
    __builtin_amdgcn_sched_barrier(0);
    __builtin_amdgcn_s_setprio(1);
    #pragma unroll
    for (int m = 0; m < 2; ++m)
      #pragma unroll
      for (int n = 0; n < 4; ++n)
        acc[m][n] = __builtin_amdgcn_mfma_f32_16x16x32_bf16(Af[m], Bf[n], acc[m][n], 0, 0, 0);
    __builtin_amdgcn_s_setprio(0);
    asm volatile("s_waitcnt lgkmcnt(0)" ::: "memory");   // A2,A3 done
    __builtin_amdgcn_sched_barrier(0);
    __builtin_amdgcn_s_setprio(1);
    #pragma unroll
    for (int m = 2; m < 4; ++m)
      #pragma unroll
      for (int n = 0; n < 4; ++n)
        acc[m][n] = __builtin_amdgcn_mfma_f32_16x16x32_bf16(Af[m], Bf[n], acc[m][n], 0, 0, 0);
    __builtin_amdgcn_s_setprio(0);
    __builtin_amdgcn_s_barrier();            // all waves' reads of buf c retired
    if (t + 2 < NT) { stageA(c, t + 2); stageB(c, t + 2); }
    if (t < NT - 2)       { asm volatile("s_waitcnt vmcnt(3)" ::: "memory"); }
    else if (t == NT - 2) { asm volatile("s_waitcnt vmcnt(0)" ::: "memory"); }
    __builtin_amdgcn_s_barrier();            // tile t+1 globally resident
  }

  // C/D layout: col = lane&15 (fr), row = quad*4 + reg
  if constexpr (EPI == 0) {
    const int sel = n0 >> 10;               // block-uniform (128-tile never straddles)
    const int cb  = (n0 & 1023) + wn * 64;
    #pragma unroll
    for (int im = 0; im < 4; ++im) {
      const int mrow = m0 + wm*64 + im*16 + quad*4;
      const int b = mrow >> 12, tt = mrow & 4095;
      const int u = tt >> 6, i = tt & 63;   // i..i+3 stay in-bucket
      #pragma unroll
      for (int nn = 0; nn < 4; ++nn) {
        const int cc = cb + nn*16 + fr;
        const int h = cc >> 7, e = cc & 127;
        const size_t bhu = (size_t)((b*8 + h)*64 + u);
        if (sel == 2) {                     // vT [u][e][i]: one 8-B store
          bf16x4 w;
          #pragma unroll
          for (int r = 0; r < 4; ++r) w[r] = (bf16)acc[im][nn][r];
          *(bf16x4*)&C2[(bhu*128 + e)*64 + i] = w;
        } else {                            // q/k [u][i][e]
          bf16* dst = (sel == 0) ? (bf16*)C0 : C1;
          #pragma unroll
          for (int r = 0; r < 4; ++r)
            dst[(bhu*64 + i + r)*128 + e] = (bf16)acc[im][nn][r];
        }
      }
    }
  } else {
    const bool f32o = input_is_fp32(xdet);
    #pragma unroll
    for (int im = 0; im < 4; ++im) {
      #pragma unroll
      for (int nn = 0; nn < 4; ++nn) {
        #pragma unroll
        for (int r = 0; r < 4; ++r) {
          const int m = m0 + wm*64 + im*16 + quad*4 + r;
          const int n = n0 + wn*64 + nn*16 + fr;
          const float val = acc[im][nn][r] + ldx(bias, n, f32o);
          if (f32o) ((float*)C0)[(size_t)m*N + n] = val;
          else      ((bf16*)C0)[(size_t)m*N + n] = (bf16)val;
        }
      }
    }
  }
}

// ---------------------------------------------------------------------------
// bksum: bkr[bh][u][e] = sum_i k[bh][u][i][e]. grid (8,32), 128 threads.
// ---------------------------------------------------------------------------
__global__ __launch_bounds__(128)
void bksum(const bf16* __restrict__ k_ws, float* __restrict__ bkr_g)
{
  const int ug = blockIdx.x, bh = blockIdx.y, t = threadIdx.x;
  const int ul = t >> 4, e0 = (t & 15) * 8;
  const int u = ug * 8 + ul;
  const bf16* p = k_ws + ((size_t)bh*64 + u)*8192 + e0;
  float acc[8];
  #pragma unroll
  for (int j = 0; j < 8; ++j) acc[j] = 0.f;
  for (int i = 0; i < 64; ++i) {
    bf16x8 kv = *(const bf16x8*)&p[i*128];
    #pragma unroll
    for (int j = 0; j < 8; ++j) acc[j] += (float)kv[j];
  }
  float* dst = bkr_g + (size_t)bh*8192 + u*128 + e0;
  #pragma unroll
  for (int j = 0; j < 8; ++j) dst[j] = acc[j];
}

// ---------------------------------------------------------------------------
// Sinkhorn R per bh (32 blocks, 256 threads). Gumbel inner expr in fp64.
// LSE phases parallelized: 4 threads/row (or col) + shfl_xor(1,2) reduce.
// ---------------------------------------------------------------------------
__global__ __launch_bounds__(256)
void sinkhorn_R(const float* __restrict__ bkr_g, const void* __restrict__ sort_w,
                const void* __restrict__ noise, float* __restrict__ R_buf,
                const void* __restrict__ xdet)
{
  const bool f32 = input_is_fp32(xdet);
  const int bh = blockIdx.x, h = bh & 7, tid = threadIdx.x;
  __shared__ float bkr[64*128];
  __shared__ float ew[128*64];
  __shared__ float R[64*65];

  for (int f = tid; f < 64*128; f += 256) bkr[f] = bkr_g[(size_t)bh*8192 + f];
  for (int f = tid; f < 128*64; f += 256) ew[f] = ldx(sort_w, (size_t)h*8192 + f, f32);
  __syncthreads();

  for (int f = tid; f < 64*64; f += 256) {
    const int u = f >> 6, v = f & 63;
    float s = 0.f;
    for (int e = 0; e < 128; ++e) s += bkr[u*128 + e] * ew[e*64 + v];
    s = fmaxf(s, 0.f);
    const float r  = logf(s + 1e-6f);
    const double nz = (double)ldx(noise, ((size_t)bh*64 + u)*64 + v, f32);
    const double t1 = log(nz + 1e-4);
    const double t2 = fmax(-t1 + 1e-4, 1e-30);
    const float g = (float)(-log(t2));
    R[u*65 + v] = (r + g) * (1.f / 0.75f);
  }
  __syncthreads();

  const int rc = tid >> 2, c4 = tid & 3;   // 4 lanes per row/col (same quad)
  for (int it = 0; it < 5; ++it) {
    {  // row LSE
      float mx = -1e30f;
      for (int v = c4; v < 64; v += 4) mx = fmaxf(mx, R[rc*65 + v]);
      mx = fmaxf(mx, __shfl_xor(mx, 1));
      mx = fmaxf(mx, __shfl_xor(mx, 2));
      float s = 0.f;
      for (int v = c4; v < 64; v += 4) s += expf(R[rc*65 + v] - mx);
      s += __shfl_xor(s, 1);
      s += __shfl_xor(s, 2);
      const float l = mx + logf(s);
      for (int v = c4; v < 64; v += 4) R[rc*65 + v] -= l;
    }
    __syncthreads();
    {  // col LSE
      float mx = -1e30f;
      for (int u = c4; u < 64; u += 4) mx = fmaxf(mx, R[u*65 + rc]);
      mx = fmaxf(mx, __shfl_xor(mx, 1));
      mx = fmaxf(mx, __shfl_xor(mx, 2));
      float s = 0.f;
      for (int u = c4; u < 64; u += 4) s += expf(R[u*65 + rc] - mx);
      s += __shfl_xor(s, 1);
      s += __shfl_xor(s, 2);
      const float l = mx + logf(s);
      for (int u = c4; u < 64; u += 4) R[u*65 + rc] -= l;
    }
    __syncthreads();
  }

  for (int f = tid; f < 64*64; f += 256) {
    const int u = f >> 6, v = f & 63;
    R_buf[(size_t)bh*4096 + f] = (u > v) ? expf(R[u*65 + v]) : 0.f;
  }
}

// ---------------------------------------------------------------------------
// permute_kv: Out[bhl][u][f] = sum_v R[bh][u][v] * X[bh][v][f]  (f = 8192)
// One block = (256-f chunk, bh-local, tensor z). R as bf16 hi+lo (K=128) for
// ~fp32 weight precision. X staged into 16-f subtiles [64 v][16 f] row-major.
// B-frags via ds_read_b64_tr_b16 (lane addr = win + 8*(lane&15) bytes).
// ---------------------------------------------------------------------------
__global__ __launch_bounds__(256)
void permute_kv(const float* __restrict__ R_buf,
                const bf16* __restrict__ Xk, const bf16* __restrict__ Xv,
                bf16* __restrict__ Ok, bf16* __restrict__ Ov, int bh0)
{
  const int tid = threadIdx.x;
  const int bhl = blockIdx.y, bh = bh0 + bhl;
  const int f0  = blockIdx.x * 256;
  const bf16* X = blockIdx.z ? Xv : Xk;
  bf16*       O = blockIdx.z ? Ov : Ok;

  __shared__ __align__(16) bf16 A_lds[64*136];    // R hi|lo, padded stride 136
  __shared__ __align__(16) bf16 X_lds[16*1048];   // 16 fgrps x [64 v][16 f]

  // stage X tile [64 v][256 f]: X_lds[fgrp][v][j] = X[v][f0 + fgrp*16 + j]
  {
    const bf16* Xg = X + (size_t)bh*524288 + f0;
    const int vb = tid >> 5, c = tid & 31;        // c: 8-f chunk
    const int dst = (c >> 1)*1048 + (c & 1)*8;
    #pragma unroll
    for (int p = 0; p < 8; ++p) {
      const int v = vb + p*8;
      *(bf16x8*)&X_lds[dst + v*16] = *(const bf16x8*)&Xg[(size_t)v*8192 + c*8];
    }
  }
  // stage R split: A[u][v]=hi(R), A[u][64+v]=lo(R)
  {
    const float* Rg = R_buf + (size_t)bh*4096;
    #pragma unroll
    for (int p = 0; p < 16; ++p) {
      const int idx = tid + p*256;
      const int uu = idx >> 6, vv = idx & 63;
      const float r = Rg[idx];
      const bf16 hi = (bf16)r;
      const float lo = r - (float)hi;
      A_lds[uu*136 + vv]      = hi;
      A_lds[uu*136 + 64 + vv] = (bf16)lo;
    }
  }
  __syncthreads();

  const int lane = tid & 63, wave = tid >> 6;
  const int fr = lane & 15, quad = lane >> 4;

  bf16x8 af[4][4];
  #pragma unroll
  for (int mt = 0; mt < 4; ++mt)
    #pragma unroll
    for (int ks = 0; ks < 4; ++ks)
      af[mt][ks] = *(const bf16x8*)&A_lds[(mt*16 + fr)*136 + ks*32 + quad*8];

  f32x4 acc[4][4];
  #pragma unroll
  for (int a = 0; a < 4; ++a)
    #pragma unroll
    for (int b = 0; b < 4; ++b) { f32x4 z = {0.f,0.f,0.f,0.f}; acc[a][b] = z; }

  #pragma unroll
  for (int nt = 0; nt < 4; ++nt) {
    const int g = wave*4 + nt;
    // per-lane addr (BYTES) = 2096*g + 256*quad + 8*fr  ->  elems: +4*fr
    const unsigned addr = (unsigned)(size_t)
        (__attribute__((address_space(3))) bf16*)&X_lds[g*1048 + quad*128 + fr*4];
    u32x2 p0, p1, p2, p3;
    asm volatile(
      "ds_read_b64_tr_b16 %0, %4\n"
      "ds_read_b64_tr_b16 %1, %4 offset:128\n"
      "ds_read_b64_tr_b16 %2, %4 offset:1024\n"
      "ds_read_b64_tr_b16 %3, %4 offset:1152\n"
      : "=&v"(p0), "=&v"(p1), "=&v"(p2), "=&v"(p3)
      : "v"(addr));
    asm volatile("s_waitcnt lgkmcnt(0)" ::: "memory");
    __builtin_amdgcn_sched_barrier(0);
    union { u32x2 u[2]; bf16x8 v; } c0, c1;
    c0.u[0] = p0; c0.u[1] = p1;               // v = quad*8 + 0..7  (v-slice 0..31)
    c1.u[0] = p2; c1.u[1] = p3;               // v-slice 32..63
    const bf16x8 b0 = c0.v, b1 = c1.v;
    #pragma unroll
    for (int mt = 0; mt < 4; ++mt) {
      acc[mt][nt] = __builtin_amdgcn_mfma_f32_16x16x32_bf16(af[mt][0], b0, acc[mt][nt], 0, 0, 0);
      acc[mt][nt] = __builtin_amdgcn_mfma_f32_16x16x32_bf16(af[mt][1], b1, acc[mt][nt], 0, 0, 0);
      acc[mt][nt] = __builtin_amdgcn_mfma_f32_16x16x32_bf16(af[mt][2], b0, acc[mt][nt], 0, 0, 0);
      acc[mt][nt] = __builtin_amdgcn_mfma_f32_16x16x32_bf16(af[mt][3], b1, acc[mt][nt], 0, 0, 0);
    }
  }

  bf16* Og = O + (size_t)bhl*524288 + f0;
  #pragma unroll
  for (int mt = 0; mt < 4; ++mt)
    #pragma unroll
    for (int nt = 0; nt < 4; ++nt)
      #pragma unroll
      for (int r = 0; r < 4; ++r)
        Og[(size_t)(mt*16 + quad*4 + r)*8192 + wave*64 + nt*16 + fr] = (bf16)acc[mt][nt][r];
}

// ---------------------------------------------------------------------------
// MFMA bucketed attention, streaming: kre/vre precomputed in global scratch.
// One block per (bh,u), 256 threads; every K/V byte read exactly once.
// T14: cold vT PV-fragments issued BEFORE dots so HBM latency hides under
// QK^T + softmax (vre is L2/L3-warm from permute; not prefetched).
// ---------------------------------------------------------------------------
__global__ __launch_bounds__(256)
void attn_mfma(const bf16* __restrict__ q_ws, const bf16* __restrict__ k_ws,
               const bf16* __restrict__ vT_ws,
               const bf16* __restrict__ kre_g, const bf16* __restrict__ vre_g,
               bf16* __restrict__ aout, int bh0)
{
  const int u = blockIdx.x, bhl = blockIdx.y, bh = bh0 + bhl;
  const int tid = threadIdx.x;
  const int lane = tid & 63, wave = tid >> 6;
  const int fr = lane & 15, quad = lane >> 4;

  __shared__ __align__(16) unsigned char smem[34048];
  float* sc = (float*)smem;                 // 64 x (stride 132)
  bf16*  pA = (bf16*)smem;                  // alias, stride 136

  const size_t tileq = ((size_t)bh *64 + u) * 8192;   // q/k/vT/aout (global bh)
  const size_t tilel = ((size_t)bhl*64 + u) * 8192;   // kre/vre (half-local bh)

  // T14 prefetch: vT frags for PV (ks = 2,3), 16 VGPR held across dots+softmax
  bf16x8 pvT[2][2];
  #pragma unroll
  for (int nt = 0; nt < 2; ++nt) {
    const int e = wave*32 + nt*16 + fr;
    #pragma unroll
    for (int k2 = 0; k2 < 2; ++k2)
      pvT[nt][k2] = *(const bf16x8*)&vT_ws[tileq + (size_t)e*64 + k2*32 + quad*8];
  }

  {
    f32x4 dacc[4][2];
    #pragma unroll
    for (int mt = 0; mt < 4; ++mt)
      #pragma unroll
      for (int nt = 0; nt < 2; ++nt) { f32x4 z = {0.f,0.f,0.f,0.f}; dacc[mt][nt] = z; }
    #pragma unroll
    for (int ks = 0; ks < 4; ++ks) {
      bf16x8 afr[4];
      #pragma unroll
      for (int mt = 0; mt < 4; ++mt)
        afr[mt] = *(const bf16x8*)&q_ws[tileq + (size_t)(mt*16 + fr)*128 + ks*32 + quad*8];
      #pragma unroll
      for (int nt = 0; nt < 2; ++nt) {
        const int j = wave*32 + nt*16 + fr;
        bf16x8 bfr;
        if (wave < 2) bfr = *(const bf16x8*)&kre_g[tilel + (size_t)j*128 + ks*32 + quad*8];
        else          bfr = *(const bf16x8*)&k_ws[tileq + (size_t)(j - 64)*128 + ks*32 + quad*8];
        #pragma unroll
        for (int mt = 0; mt < 4; ++mt)
          dacc[mt][nt] = __builtin_amdgcn_mfma_f32_16x16x32_bf16(afr[mt], bfr, dacc[mt][nt], 0, 0, 0);
      }
    }
    #pragma unroll
    for (int mt = 0; mt < 4; ++mt)
      #pragma unroll
      for (int nt = 0; nt < 2; ++nt)
        #pragma unroll
        for (int r = 0; r < 4; ++r)
          sc[(mt*16 + quad*4 + r)*132 + wave*32 + nt*16 + fr] = dacc[mt][nt][r] * 0.03125f;
  }
  __syncthreads();

  {
    const int i = tid >> 2, jc = tid & 3;
    float pv[32];
    float mx = -1e30f;
    #pragma unroll
    for (int t = 0; t < 32; ++t) { pv[t] = sc[i*132 + jc + t*4]; mx = fmaxf(mx, pv[t]); }
    mx = fmaxf(mx, __shfl_xor(mx, 1));
    mx = fmaxf(mx, __shfl_xor(mx, 2));
    float s = 0.f;
    #pragma unroll
    for (int t = 0; t < 32; ++t) { pv[t] = expf(pv[t] - mx); s += pv[t]; }
    s += __shfl_xor(s, 1);
    s += __shfl_xor(s, 2);
    const float inv = 1.f / s;
    __syncthreads();
    #pragma unroll
    for (int t = 0; t < 32; ++t) pA[i*136 + jc + t*4] = (bf16)(pv[t] * inv);
  }
  __syncthreads();

  {
    f32x4 oacc[4][2];
    #pragma unroll
    for (int mt = 0; mt < 4; ++mt)
      #pragma unroll
      for (int nt = 0; nt < 2; ++nt) { f32x4 z = {0.f,0.f,0.f,0.f}; oacc[mt][nt] = z; }
    #pragma unroll
    for (int ks = 0; ks < 4; ++ks) {
      bf16x8 afr[4];
      #pragma unroll
      for (int mt = 0; mt < 4; ++mt)
        afr[mt] = *(const bf16x8*)&pA[(mt*16 + fr)*136 + ks*32 + quad*8];
      #pragma unroll
      for (int nt = 0; nt < 2; ++nt) {
        bf16x8 bfr;
        if (ks < 2) {
          const int e = wave*32 + nt*16 + fr;
          bfr = *(const bf16x8*)&vre_g[tilel + (size_t)e*64 + ks*32 + quad*8];
        } else {
          bfr = pvT[nt][ks - 2];
        }
        #pragma unroll
        for (int mt = 0; mt < 4; ++mt)
          oacc[mt][nt] = __builtin_amdgcn_mfma_f32_16x16x32_bf16(afr[mt], bfr, oacc[mt][nt], 0, 0, 0);
      }
    }
    __syncthreads();
    #pragma unroll
    for (int mt = 0; mt < 4; ++mt)
      #pragma unroll
      for (int nt = 0; nt < 2; ++nt)
        #pragma unroll
        for (int r = 0; r < 4; ++r)
          pA[(mt*16 + quad*4 + r)*136 + wave*32 + nt*16 + fr] = (bf16)oacc[mt][nt][r];
  }
  __syncthreads();

  {
    const int b = bh >> 3, h = bh & 7;
    #pragma unroll
    for (int r = 0; r < 4; ++r) {
      const int f = r*2048 + tid*8;
      const int i = f >> 7, e0 = f & 127;
      bf16x8 w = *(const bf16x8*)&pA[i*136 + e0];
      *(bf16x8*)&aout[((size_t)(b*4096 + u*64 + i))*1024 + h*128 + e0] = w;
    }
  }
}

// ---------------------------------------------------------------------------
extern "C" void kernel_launch(void* const* d_in, const int* in_sizes, int n_in,
                              void* d_out, int out_size, void* d_ws, size_t ws_size,
                              hipStream_t stream)
{
  (void)in_sizes; (void)n_in; (void)out_size; (void)ws_size;
  const void* x      = d_in[0];   // (4,4096,1024)
  const void* w_qkv  = d_in[1];   // (3072,1024)
  const void* sort_w = d_in[2];   // (1,8,128,64)
  const void* w_out  = d_in[3];   // (1024,1024)
  const void* b_out  = d_in[4];   // (1024,)
  const void* noise  = d_in[5];   // (32,64,64)

  char* ws = (char*)d_ws;
  const size_t TEN = (size_t)32*64*64*128;     // 16,777,216 elements
  const size_t HEN = TEN / 2;                  // per-half kre/vre elements
  bf16* q_ws  = (bf16*)ws;
  bf16* k_ws  = q_ws + TEN;
  bf16* vT_ws = k_ws + TEN;                    // [bh][u][e][i]
  bf16* xa_ws = vT_ws + TEN;                   // x-as-bf16, later attn out (b,t,d)

  // bkr/R live in the xa tail (b=3 rows of aout, overwritten only by attn h2)
  float* bkr_g = (float*)((char*)xa_ws + (size_t)30*1024*1024);   // 1 MiB
  float* R_buf = (float*)((char*)xa_ws + (size_t)31*1024*1024);   // 512 KiB
  // d_out scratch
  bf16* wqkv_bf = (bf16*)((char*)d_out + (1536<<10));  // 6 MiB, dead after gemm1
  bf16* kre = (bf16*)d_out;                            // 16 MiB per half
  bf16* vre = kre + HEN;                               // 16 MiB per half
  bf16* wout_bf = k_ws;                                // reused after attn

  convert_pair<<<9728, 256, 0, stream>>>(x, xa_ws, w_qkv, wqkv_bf, x);

  gemm256<0><<<dim3(24,64), 512, 0, stream>>>(xa_ws, wqkv_bf, nullptr,
                                              q_ws, k_ws, vT_ws, x, 16384, 3072, 1024);

  bksum<<<dim3(8,32), 128, 0, stream>>>(k_ws, bkr_g);
  sinkhorn_R<<<32, 256, 0, stream>>>(bkr_g, sort_w, noise, R_buf, x);

  // half 1: bh 0..15 (writes aout b=0,1 -> xa[0,16Mi), R stays intact)
  permute_kv<<<dim3(32,16,2), 256, 0, stream>>>(R_buf, k_ws, vT_ws, kre, vre, 0);
  attn_mfma<<<dim3(64,16), 256, 0, stream>>>(q_ws, k_ws, vT_ws, kre, vre, xa_ws, 0);
  // half 2: bh 16..31 (attn clobbers xa tail incl. bkr/R after R is consumed)
  permute_kv<<<dim3(32,16,2), 256, 0, stream>>>(R_buf, k_ws, vT_ws, kre, vre, 16);
  attn_mfma<<<dim3(64,16), 256, 0, stream>>>(q_ws, k_ws, vT_ws, kre, vre, xa_ws, 16);

  convert_to_bf16<<<512, 256, 0, stream>>>(w_out, wout_bf, x);
  gemm256<1><<<dim3(8,64), 512, 0, stream>>>(xa_ws, wout_bf, b_out,
                                             d_out, nullptr, nullptr, x, 16384, 1024, 1024);
}